// Round 6
// baseline (354.328 us; speedup 1.0000x reference)
//
#include <hip/hip_runtime.h>
#include <hip/hip_bf16.h>

#define N_NODES 100000
#define N_EDGES 1600000
#define N_TOT   (N_EDGES + N_NODES)   // edges + self loops
#define F_IN    256
#define F1      64     // H1*C1
#define H1      8
#define C1      8
#define F2      32
#define SLOPE   0.2f

#define NB_G    ((N_NODES + 255) / 256)           // 391 gemm blocks

// counting-sort CSR build (no global atomics)
#define EB      4096                               // edges per P1/P3 block
#define NB1     ((N_EDGES + EB - 1) / EB)          // 391
#define BW      256                                // nodes per bucket
#define NBKT    ((N_NODES + BW - 1) / BW)          // 391

typedef unsigned int  uint;
typedef unsigned short ushort;
typedef __attribute__((ext_vector_type(8))) short bf16x8;
typedef __attribute__((ext_vector_type(4))) float f32x4;
typedef __attribute__((ext_vector_type(2))) float f32x2;

__device__ inline ushort f2bf(float f) {               // RNE float->bf16
    uint u = __float_as_uint(f);
    uint r = u + 0x7fffu + ((u >> 16) & 1u);
    return (ushort)(r >> 16);
}
__device__ inline float bflo(uint u) { return __uint_as_float(u << 16); }
__device__ inline float bfhi(uint u) { return __uint_as_float(u & 0xffff0000u); }
__device__ inline uint pk2bf(float a, float b) {
    __hip_bfloat162 h = __float22bfloat162_rn(make_float2(a, b));
    union { __hip_bfloat162 h; uint u; } cv; cv.h = h;
    return cv.u;
}

// Block-wide exclusive scan of colsum[NBKT] -> sb[0..NBKT] (sb[NBKT]=total).
// 256 threads; thread t owns elements 2t, 2t+1. sc = 256-int scratch.
__device__ inline void bucket_bases(const int* __restrict__ colsum,
                                    int* sc, int* sb, int tid) {
    const int i0 = 2 * tid, i1 = 2 * tid + 1;
    const int a0 = (i0 < NBKT) ? colsum[i0] : 0;
    const int a1 = (i1 < NBKT) ? colsum[i1] : 0;
    sc[tid] = a0 + a1;
    __syncthreads();
    for (int off = 1; off < 256; off <<= 1) {
        int t = (tid >= off) ? sc[tid - off] : 0;
        __syncthreads();
        sc[tid] += t;
        __syncthreads();
    }
    const int excl = sc[tid] - (a0 + a1);
    if (i0 < NBKT)  sb[i0] = excl;
    if (i1 <= NBKT) sb[i1] = excl + a0;       // writes sb[NBKT] (=total) too
    __syncthreads();
}

// ---------------------------------------------------------------------------
// Launch 1: blocks [0,NB1) = P1 bucket-count (LDS histogram, plain stores);
// block NB1 = W1 -> swizzled bf16 pre-convert (so the gemm's LDS staging in
// launch 4 is a straight vector copy instead of 64 scalar cvt/thread at low
// occupancy). No global atomics anywhere.
// ---------------------------------------------------------------------------
__global__ __launch_bounds__(256) void k_p1w(
        const int* __restrict__ ei, const float* __restrict__ W1,
        int* __restrict__ bcnt, ushort* __restrict__ w1b) {
    __shared__ int H[NBKT];
    const int tid = threadIdx.x;
    if (blockIdx.x == NB1) {                       // ---- W1 convert ----
        for (int i = 0; i < 64; ++i) {
            const int e = i * 256 + tid;           // e = k*64 + n
            const int k = e >> 6, n = e & 63;
            w1b[((k >> 3) * 64 + n) * 8 + (k & 7)] = f2bf(W1[e]);
        }
        return;
    }
    const int blk = blockIdx.x;
    for (int j = tid; j < NBKT; j += 256) H[j] = 0;
    __syncthreads();
    const int e0 = blk * EB;
    const int lim = (e0 + EB < N_EDGES) ? e0 + EB : N_EDGES;
    for (int i = e0 + tid; i < lim; i += 256)
        atomicAdd(&H[ei[N_EDGES + i] >> 8], 1);    // LDS atomic
    __syncthreads();
    for (int j = tid; j < NBKT; j += 256)
        bcnt[j * NB1 + blk] = H[j];
}

// ---------------------------------------------------------------------------
// P2: per-bucket exclusive scan of bcnt[bucket][*] across blocks (in place)
// + column sums. One wave per bucket.
// ---------------------------------------------------------------------------
__global__ __launch_bounds__(64) void k_p2(
        int* __restrict__ bcnt, int* __restrict__ colsum) {
    const int col = blockIdx.x, lane = threadIdx.x;
    int carry = 0;
    for (int c0 = 0; c0 < NB1; c0 += 64) {
        const int idx = c0 + lane;
        const int v = (idx < NB1) ? bcnt[col * NB1 + idx] : 0;
        int s = v;
#pragma unroll
        for (int off = 1; off < 64; off <<= 1) {
            int u = __shfl_up(s, off);
            if (lane >= off) s += u;
        }
        if (idx < NB1) bcnt[col * NB1 + idx] = carry + s - v;
        carry += __shfl(s, 63);
    }
    if (lane == 0) colsum[col] = carry;
}

// ---------------------------------------------------------------------------
// P3: bucket scatter. Each block re-reads its EB edges, places PACKED
// (dst&255)<<24 | src into bucket-ordered tmp via LDS cursors.
// ---------------------------------------------------------------------------
__global__ __launch_bounds__(256) void k_p3(
        const int* __restrict__ ei, const int* __restrict__ bcnt,
        const int* __restrict__ colsum, uint* __restrict__ tmp) {
    __shared__ int sc[256];
    __shared__ int cur[NBKT + 1];
    const int tid = threadIdx.x, blk = blockIdx.x;
    bucket_bases(colsum, sc, cur, tid);
    for (int b = tid; b < NBKT; b += 256) cur[b] += bcnt[b * NB1 + blk];
    __syncthreads();
    const int e0 = blk * EB;
    const int lim = (e0 + EB < N_EDGES) ? e0 + EB : N_EDGES;
    for (int i = e0 + tid; i < lim; i += 256) {
        const int s = ei[i], d = ei[N_EDGES + i];
        const int pos = atomicAdd(&cur[d >> 8], 1);     // LDS atomic
        tmp[pos] = ((uint)(d & 255) << 24) | (uint)s;
    }
}

// ---------------------------------------------------------------------------
// Launch 4: blocks [0,NBKT) = final CSR placement (count, local scan with
// off_b = sb[b] + b*256, self loop slot 0, place); blocks [NBKT,NBKT+NB_G)
// = MFMA gemm (h1 = x@W1 + s1/d1 dots) staged from pre-swizzled w1b.
// Fusing the gemm HERE (instead of launch 1) lets the p2/p3 chain start
// right after the cheap histogram, and hides k_final under the gemm.
// ---------------------------------------------------------------------------
__global__ __launch_bounds__(256) void k_final_gemm(
        const uint* __restrict__ tmp, const int* __restrict__ colsum,
        int* __restrict__ row_ptr, int* __restrict__ srcs,
        const float* __restrict__ x, const ushort* __restrict__ w1b,
        const float* __restrict__ as1, const float* __restrict__ ad1,
        ushort* __restrict__ h1b, float* __restrict__ s1,
        float* __restrict__ d1) {
    __shared__ union {
        struct { int sc[256]; int sb[NBKT + 1]; int cur[BW]; } f;
        ushort B[F_IN * F1];        // 32 KB: W1 bf16 swizzled
        ushort S[4][64][66];        // 33.8 KB: per-wave h staging (pad 66)
    } sm;
    const int tid = threadIdx.x;

    if (blockIdx.x < NBKT) {                       // ---- final placement ----
        const int b = blockIdx.x;
        bucket_bases(colsum, sm.f.sc, sm.f.sb, tid);
        sm.f.cur[tid] = 0;
        __syncthreads();
        const int lo = sm.f.sb[b], hi = sm.f.sb[b + 1];
        for (int i = lo + tid; i < hi; i += 256)
            atomicAdd(&sm.f.cur[tmp[i] >> 24], 1);      // LDS atomic
        __syncthreads();
        const int n = b * BW + tid;
        const int myc = sm.f.cur[tid];
        const int v = (n < N_NODES) ? myc + 1 : 0;      // +1 = self loop
        __syncthreads();
        sm.f.sc[tid] = v;
        __syncthreads();
        for (int off = 1; off < 256; off <<= 1) {
            int t = (tid >= off) ? sm.f.sc[tid - off] : 0;
            __syncthreads();
            sm.f.sc[tid] += t;
            __syncthreads();
        }
        const int rp = lo + b * BW + (sm.f.sc[tid] - v);
        if (n < N_NODES) {
            row_ptr[n] = rp;
            srcs[rp] = n;                               // self loop slot 0
        }
        if (b == NBKT - 1 && tid == 255) row_ptr[N_NODES] = N_TOT;
        sm.f.cur[tid] = rp + 1;                         // edge cursor
        __syncthreads();
        for (int i = lo + tid; i < hi; i += 256) {
            const uint u = tmp[i];
            const int pos = atomicAdd(&sm.f.cur[u >> 24], 1);   // LDS atomic
            srcs[pos] = (int)(u & 0xFFFFFFu);
        }
        return;
    }

    // ---- MFMA gemm part ----
    {   // stage pre-swizzled W1: straight 32 KB vector copy
        const uint4* s4 = (const uint4*)w1b;
        uint4* d4 = (uint4*)sm.B;
#pragma unroll
        for (int i = 0; i < 8; ++i)
            d4[i * 256 + tid] = s4[i * 256 + tid];
    }
    __syncthreads();

    const int wave = tid >> 6, lane = tid & 63;
    const int q = lane >> 4, ln = lane & 15;
    const int rowbase = (blockIdx.x - NBKT) * 256 + wave * 64;

    f32x4 acc[4][4];
#pragma unroll
    for (int mt = 0; mt < 4; ++mt)
#pragma unroll
        for (int nt = 0; nt < 4; ++nt) acc[mt][nt] = (f32x4){0.f, 0.f, 0.f, 0.f};

    int rows[4];
#pragma unroll
    for (int mt = 0; mt < 4; ++mt) {
        const int r = rowbase + mt * 16 + ln;
        rows[mt] = r < N_NODES ? r : N_NODES - 1;
    }

    for (int t = 0; t < 8; ++t) {                  // K-loop: 8 x 32
        bf16x8 bfr[4];
#pragma unroll
        for (int nt = 0; nt < 4; ++nt)
            bfr[nt] = *(const bf16x8*)&sm.B[((t * 4 + q) * 64 + nt * 16 + ln) * 8];
#pragma unroll
        for (int mt = 0; mt < 4; ++mt) {
            const float4* ap = (const float4*)(x + (size_t)rows[mt] * F_IN + t * 32 + q * 8);
            const float4 a0 = ap[0], a1 = ap[1];
            uint4 au = make_uint4(pk2bf(a0.x, a0.y), pk2bf(a0.z, a0.w),
                                  pk2bf(a1.x, a1.y), pk2bf(a1.z, a1.w));
            bf16x8 af = *(bf16x8*)&au;
#pragma unroll
            for (int nt = 0; nt < 4; ++nt)
                acc[mt][nt] = __builtin_amdgcn_mfma_f32_16x16x32_bf16(
                                  af, bfr[nt], acc[mt][nt], 0, 0, 0);
        }
    }
    __syncthreads();

    // stage h (bf16): C/D layout col=lane&15, row=q*4+r
#pragma unroll
    for (int mt = 0; mt < 4; ++mt)
#pragma unroll
        for (int nt = 0; nt < 4; ++nt)
#pragma unroll
            for (int r = 0; r < 4; ++r)
                sm.S[wave][mt * 16 + q * 4 + r][nt * 16 + ln] = f2bf(acc[mt][nt][r]);
    __syncthreads();

    const int node = rowbase + lane;
    if (node >= N_NODES) return;
    const uint* srow = (const uint*)&sm.S[wave][lane][0];
    float sacc[H1], dacc[H1];
#pragma unroll
    for (int h = 0; h < H1; ++h) { sacc[h] = 0.f; dacc[h] = 0.f; }
    uint4* hout = (uint4*)(h1b + (size_t)node * F1);
#pragma unroll
    for (int p4 = 0; p4 < 8; ++p4) {               // p4 == head index
        const uint u0 = srow[p4 * 4 + 0], u1 = srow[p4 * 4 + 1];
        const uint u2 = srow[p4 * 4 + 2], u3 = srow[p4 * 4 + 3];
        hout[p4] = make_uint4(u0, u1, u2, u3);
        const float c[8] = {bflo(u0), bfhi(u0), bflo(u1), bfhi(u1),
                            bflo(u2), bfhi(u2), bflo(u3), bfhi(u3)};
#pragma unroll
        for (int j = 0; j < 8; ++j) {
            sacc[p4] += c[j] * as1[p4 * 8 + j];
            dacc[p4] += c[j] * ad1[p4 * 8 + j];
        }
    }
    float4* s4 = (float4*)(s1 + (size_t)node * H1);
    float4* d4 = (float4*)(d1 + (size_t)node * H1);
    s4[0] = make_float4(sacc[0], sacc[1], sacc[2], sacc[3]);
    s4[1] = make_float4(sacc[4], sacc[5], sacc[6], sacc[7]);
    d4[0] = make_float4(dacc[0], dacc[1], dacc[2], dacc[3]);
    d4[1] = make_float4(dacc[4], dacc[5], dacc[6], dacc[7]);
}

// ---------------------------------------------------------------------------
// K_agg1 (+ fused node GEMM): 8 lanes/edge, lane = head, uint4 h1 loads
// (128B aligned rows; s1 separate 3.2MB = per-XCD L2 resident), f32x2
// accumulators, reduce-scatter epilogue, fused 64x32 W2 GEMM + s2/d2 dots.
// ---------------------------------------------------------------------------
__global__ __launch_bounds__(256) void k_agg1(
        const int* __restrict__ row_ptr, const int* __restrict__ srcs,
        const ushort* __restrict__ h1b, const float* __restrict__ s1,
        const float* __restrict__ d1, const float* __restrict__ b1,
        const float* __restrict__ W2, const float* __restrict__ as2,
        const float* __restrict__ ad2,
        ushort* __restrict__ h2b, float* __restrict__ s2,
        float* __restrict__ d2) {
    __shared__ float sx[4][64];                    // per-wave x2 row (f32)
    const int wid = (blockIdx.x * 256 + threadIdx.x) >> 6;
    if (wid >= N_NODES) return;
    const int w = threadIdx.x >> 6;
    const int lane = threadIdx.x & 63;
    const int q = lane >> 3;          // edge group 0..7
    const int c = lane & 7;           // head (= uint4 idx: channels 8c..8c+7)
    const float dh = d1[(size_t)wid * H1 + c];
    const int beg = row_ptr[wid], end = row_ptr[wid + 1];
    const uint4* hv = (const uint4*)h1b;      // 8 uint4 per node
    f32x2 A0 = {0.f, 0.f}, A1 = {0.f, 0.f}, A2 = {0.f, 0.f}, A3 = {0.f, 0.f};
    float z = 0.f;
    int i = beg + q;
    for (; i + 8 < end; i += 16) {            // edges i, i+8
        const int sA = srcs[i], sB = srcs[i + 8];
        float eA = s1[(size_t)sA * H1 + c] + dh;
        float eB = s1[(size_t)sB * H1 + c] + dh;
        eA = fmaxf(eA, SLOPE * eA);           // leaky (slope<1)
        eB = fmaxf(eB, SLOPE * eB);
        const float xA = __expf(eA), xB = __expf(eB);
        const uint4 UA = hv[(size_t)sA * 8 + c];
        const uint4 UB = hv[(size_t)sB * 8 + c];
        z += xA + xB;
        const f32x2 xa = {xA, xA}, xb = {xB, xB};
        A0 += xa * (f32x2){bflo(UA.x), bfhi(UA.x)};
        A1 += xa * (f32x2){bflo(UA.y), bfhi(UA.y)};
        A2 += xa * (f32x2){bflo(UA.z), bfhi(UA.z)};
        A3 += xa * (f32x2){bflo(UA.w), bfhi(UA.w)};
        A0 += xb * (f32x2){bflo(UB.x), bfhi(UB.x)};
        A1 += xb * (f32x2){bflo(UB.y), bfhi(UB.y)};
        A2 += xb * (f32x2){bflo(UB.z), bfhi(UB.z)};
        A3 += xb * (f32x2){bflo(UB.w), bfhi(UB.w)};
    }
    for (; i < end; i += 8) {
        const int sA = srcs[i];
        float eA = s1[(size_t)sA * H1 + c] + dh;
        eA = fmaxf(eA, SLOPE * eA);
        const float xA = __expf(eA);
        const uint4 UA = hv[(size_t)sA * 8 + c];
        z += xA;
        const f32x2 xa = {xA, xA};
        A0 += xa * (f32x2){bflo(UA.x), bfhi(UA.x)};
        A1 += xa * (f32x2){bflo(UA.y), bfhi(UA.y)};
        A2 += xa * (f32x2){bflo(UA.z), bfhi(UA.z)};
        A3 += xa * (f32x2){bflo(UA.w), bfhi(UA.w)};
    }
    // ---- reduce-scatter over rep bits 3,4,5: lane ends with channel j ----
    f32x2 r0, r1;
    {   // off=8
        const bool hi = lane & 8;
        f32x2 snd0 = hi ? A0 : A2, snd1 = hi ? A1 : A3;
        const f32x2 kp0 = hi ? A2 : A0, kp1 = hi ? A3 : A1;
        snd0.x = __shfl_xor(snd0.x, 8); snd0.y = __shfl_xor(snd0.y, 8);
        snd1.x = __shfl_xor(snd1.x, 8); snd1.y = __shfl_xor(snd1.y, 8);
        r0 = kp0 + snd0; r1 = kp1 + snd1;
    }
    {   // off=16
        const bool hi = lane & 16;
        f32x2 snd = hi ? r0 : r1;
        const f32x2 kp = hi ? r1 : r0;
        snd.x = __shfl_xor(snd.x, 16); snd.y = __shfl_xor(snd.y, 16);
        r0 = kp + snd;
    }
    float sv;
    {   // off=32
        const bool hi = lane & 32;
        float snd = hi ? r0.x : r0.y;
        const float kp = hi ? r0.y : r0.x;
        snd = __shfl_xor(snd, 32);
        sv = kp + snd;
    }
    z += __shfl_xor(z, 8); z += __shfl_xor(z, 16); z += __shfl_xor(z, 32);

    const int j = (((lane >> 3) & 1) << 2) | (((lane >> 4) & 1) << 1)
                | ((lane >> 5) & 1);
    const int xi = c * 8 + j;                  // this lane's x2 element
    const float zi = 1.f / (z + 1e-16f);
    float xv = sv * zi + b1[xi];
    xv = xv > 0.f ? xv : __expf(xv) - 1.f;     // elu, all 64 lanes (1 each)
    sx[w][xi] = xv;                            // permutation: conflict-free
    __builtin_amdgcn_wave_barrier();           // in-wave LDS RAW ordering

    // fused node GEMM: h2[oc] = sum_k x2[k] * W2[k][oc]  (lane: kh half, oc)
    const int kh = lane >> 5;          // K half 0..1
    const int oc = lane & 31;          // output channel
    const float4* sxv = (const float4*)&sx[w][kh * 32];   // broadcast reads
    const float* wp0 = W2 + (size_t)(kh * 32) * F2 + oc;  // coalesced 128B/half
    float acc = 0.f;
#pragma unroll
    for (int k4 = 0; k4 < 8; ++k4) {
        const float4 xv4 = sxv[k4];
        const float* wp = wp0 + (size_t)k4 * 4 * F2;
        acc += xv4.x * wp[0]      + xv4.y * wp[F2]
             + xv4.z * wp[2 * F2] + xv4.w * wp[3 * F2];
    }
    acc += __shfl_xor(acc, 32);        // combine K halves; all lanes have h2[oc]

    float sA2 = acc * as2[oc], dA2 = acc * ad2[oc];
#pragma unroll
    for (int off = 1; off <= 16; off <<= 1) {
        sA2 += __shfl_xor(sA2, off);
        dA2 += __shfl_xor(dA2, off);
    }
    const float accp = __shfl_xor(acc, 1);     // partner channel (oc^1)
    if (lane < 32 && !(lane & 1))
        *(uint*)&h2b[(size_t)wid * F2 + oc] = pk2bf(acc, accp);
    if (lane == 0) { s2[wid] = sA2; d2[wid] = dA2; }
}

// ---------------------------------------------------------------------------
// K_agg2: 4 lanes/edge (16 groups), uint4 loads, f32x2 accumulators,
// reduce-scatter epilogue -> 1 exp/lane softmax tail. Writes d_out.
// ---------------------------------------------------------------------------
__global__ __launch_bounds__(256) void k_agg2(
        const int* __restrict__ row_ptr, const int* __restrict__ srcs,
        const ushort* __restrict__ h2b, const float* __restrict__ s2,
        const float* __restrict__ d2, const float* __restrict__ b2,
        float* __restrict__ out) {
    const int wid = (blockIdx.x * 256 + threadIdx.x) >> 6;
    if (wid >= N_NODES) return;
    const int lane = threadIdx.x & 63;
    const int q = lane >> 2;          // edge group 0..15
    const int c = lane & 3;           // uint4 idx: channels 8c..8c+7
    const float dn = d2[wid];
    const int beg = row_ptr[wid], end = row_ptr[wid + 1];
    const uint4* hv = (const uint4*)h2b;      // 4 uint4 per node
    f32x2 A0 = {0.f, 0.f}, A1 = {0.f, 0.f}, A2 = {0.f, 0.f}, A3 = {0.f, 0.f};
    float z = 0.f;
    int i = beg + q;
    for (; i + 16 < end; i += 32) {           // edges i, i+16
        const int sA = srcs[i], sB = srcs[i + 16];
        float eA = s2[sA] + dn;
        float eB = s2[sB] + dn;
        eA = fmaxf(eA, SLOPE * eA);
        eB = fmaxf(eB, SLOPE * eB);
        const float xA = __expf(eA), xB = __expf(eB);
        const uint4 UA = hv[(size_t)sA * 4 + c];
        const uint4 UB = hv[(size_t)sB * 4 + c];
        z += xA + xB;
        const f32x2 xa = {xA, xA}, xb = {xB, xB};
        A0 += xa * (f32x2){bflo(UA.x), bfhi(UA.x)};
        A1 += xa * (f32x2){bflo(UA.y), bfhi(UA.y)};
        A2 += xa * (f32x2){bflo(UA.z), bfhi(UA.z)};
        A3 += xa * (f32x2){bflo(UA.w), bfhi(UA.w)};
        A0 += xb * (f32x2){bflo(UB.x), bfhi(UB.x)};
        A1 += xb * (f32x2){bflo(UB.y), bfhi(UB.y)};
        A2 += xb * (f32x2){bflo(UB.z), bfhi(UB.z)};
        A3 += xb * (f32x2){bflo(UB.w), bfhi(UB.w)};
    }
    for (; i < end; i += 16) {
        const int sA = srcs[i];
        float eA = s2[sA] + dn;
        eA = fmaxf(eA, SLOPE * eA);
        const float xA = __expf(eA);
        const uint4 UA = hv[(size_t)sA * 4 + c];
        z += xA;
        const f32x2 xa = {xA, xA};
        A0 += xa * (f32x2){bflo(UA.x), bfhi(UA.x)};
        A1 += xa * (f32x2){bflo(UA.y), bfhi(UA.y)};
        A2 += xa * (f32x2){bflo(UA.z), bfhi(UA.z)};
        A3 += xa * (f32x2){bflo(UA.w), bfhi(UA.w)};
    }
    // ---- reduce-scatter over rep bits 2,3,4; plain combine over bit5 ----
    f32x2 r0, r1;
    {
        const bool hi = lane & 4;
        f32x2 snd0 = hi ? A0 : A2, snd1 = hi ? A1 : A3;
        const f32x2 kp0 = hi ? A2 : A0, kp1 = hi ? A3 : A1;
        snd0.x = __shfl_xor(snd0.x, 4); snd0.y = __shfl_xor(snd0.y, 4);
        snd1.x = __shfl_xor(snd1.x, 4); snd1.y = __shfl_xor(snd1.y, 4);
        r0 = kp0 + snd0; r1 = kp1 + snd1;
    }
    {
        const bool hi = lane & 8;
        f32x2 snd = hi ? r0 : r1;
        const f32x2 kp = hi ? r1 : r0;
        snd.x = __shfl_xor(snd.x, 8); snd.y = __shfl_xor(snd.y, 8);
        r0 = kp + snd;
    }
    float sv;
    {
        const bool hi = lane & 16;
        float snd = hi ? r0.x : r0.y;
        const float kp = hi ? r0.y : r0.x;
        snd = __shfl_xor(snd, 16);
        sv = kp + snd;
    }
    sv += __shfl_xor(sv, 32);          // lanes l, l^32 now duplicate
    z += __shfl_xor(z, 4); z += __shfl_xor(z, 8);
    z += __shfl_xor(z, 16); z += __shfl_xor(z, 32);

    const int j = (((lane >> 2) & 1) << 2) | (((lane >> 3) & 1) << 1)
                | ((lane >> 4) & 1);
    const int elem = c * 8 + j;        // this lane's class (dup over bit5)
    const float zi = 1.f / (z + 1e-16f);
    const float v = sv * zi + b2[elem];
    // log-softmax over the 32 classes: each 32-lane half holds all 32 once.
    float m = v;
#pragma unroll
    for (int off = 1; off <= 16; off <<= 1) m = fmaxf(m, __shfl_xor(m, off));
    float ssum = __expf(v - m);
#pragma unroll
    for (int off = 1; off <= 16; off <<= 1) ssum += __shfl_xor(ssum, off);
    const float lse = m + __logf(ssum);
    if (lane < 32) out[(size_t)wid * F2 + elem] = v - lse;
}

extern "C" void kernel_launch(void* const* d_in, const int* in_sizes, int n_in,
                              void* d_out, int out_size, void* d_ws, size_t ws_size,
                              hipStream_t stream) {
    const float* x   = (const float*)d_in[0];
    const int*   ei  = (const int*)d_in[1];
    const float* W1  = (const float*)d_in[2];
    const float* as1 = (const float*)d_in[3];
    const float* ad1 = (const float*)d_in[4];
    const float* b1  = (const float*)d_in[5];
    const float* W2  = (const float*)d_in[6];
    const float* as2 = (const float*)d_in[7];
    const float* ad2 = (const float*)d_in[8];
    const float* b2  = (const float*)d_in[9];
    float* out = (float*)d_out;

    // Workspace layout
    ushort* h1b = (ushort*)d_ws;                   // N*64 bf16 (128B rows)
    ushort* h2b = h1b + (size_t)N_NODES * F1;      // N*32 bf16
    ushort* w1b = h2b + (size_t)N_NODES * F2;      // 16384 bf16 (swizzled W1)
    float*  s1  = (float*)(w1b + F_IN * F1);       // N*8
    float*  d1  = s1 + (size_t)N_NODES * H1;       // N*8
    float*  s2  = d1 + (size_t)N_NODES * H1;       // N
    float*  d2  = s2 + N_NODES;                    // N
    uint*   tmp = (uint*)(d2 + N_NODES);           // N_EDGES (packed)
    int* row_ptr = (int*)(tmp + N_EDGES);          // N+1
    int* colsum  = row_ptr + N_NODES + 1;          // NBKT
    int* bcnt    = colsum + NBKT;                  // NBKT*NB1
    int* srcs    = bcnt + (size_t)NBKT * NB1;      // N_TOT

    const int nb_w = (N_NODES * 64 + 255) / 256;   // one wave per node

    k_p1w<<<NB1 + 1, 256, 0, stream>>>(ei, W1, bcnt, w1b);
    k_p2<<<NBKT, 64, 0, stream>>>(bcnt, colsum);
    k_p3<<<NB1, 256, 0, stream>>>(ei, bcnt, colsum, tmp);
    k_final_gemm<<<NBKT + NB_G, 256, 0, stream>>>(tmp, colsum, row_ptr, srcs,
                                                  x, w1b, as1, ad1,
                                                  h1b, s1, d1);
    k_agg1<<<nb_w, 256, 0, stream>>>(row_ptr, srcs, h1b, s1, d1, b1,
                                     W2, as2, ad2, h2b, s2, d2);
    k_agg2<<<nb_w, 256, 0, stream>>>(row_ptr, srcs, h2b, s2, d2, b2, out);
}

// Round 7
// 347.632 us; speedup vs baseline: 1.0193x; 1.0193x over previous
//
#include <hip/hip_runtime.h>
#include <hip/hip_bf16.h>

#define N_NODES 100000
#define N_EDGES 1600000
#define N_TOT   (N_EDGES + N_NODES)   // edges + self loops
#define F_IN    256
#define F1      64     // H1*C1
#define H1      8
#define C1      8
#define F2      32
#define SLOPE   0.2f

#define NB_G    ((N_NODES + 255) / 256)           // 391 gemm blocks
#define NB_X    3125                               // x->bf16 convert blocks (25.6e6/8192)

// counting-sort CSR build (no global atomics)
#define EB      4096                               // edges per P1/P3 block
#define NB1     ((N_EDGES + EB - 1) / EB)          // 391
#define BW      256                                // nodes per bucket
#define NBKT    ((N_NODES + BW - 1) / BW)          // 391

typedef unsigned int  uint;
typedef unsigned short ushort;
typedef __attribute__((ext_vector_type(8))) short bf16x8;
typedef __attribute__((ext_vector_type(4))) float f32x4;
typedef __attribute__((ext_vector_type(2))) float f32x2;

__device__ inline ushort f2bf(float f) {               // RNE float->bf16
    uint u = __float_as_uint(f);
    uint r = u + 0x7fffu + ((u >> 16) & 1u);
    return (ushort)(r >> 16);
}
__device__ inline float bflo(uint u) { return __uint_as_float(u << 16); }
__device__ inline float bfhi(uint u) { return __uint_as_float(u & 0xffff0000u); }
__device__ inline uint pk2bf(float a, float b) {
    __hip_bfloat162 h = __float22bfloat162_rn(make_float2(a, b));
    union { __hip_bfloat162 h; uint u; } cv; cv.h = h;
    return cv.u;
}

// Block-wide exclusive scan of colsum[NBKT] -> sb[0..NBKT] (sb[NBKT]=total).
__device__ inline void bucket_bases(const int* __restrict__ colsum,
                                    int* sc, int* sb, int tid) {
    const int i0 = 2 * tid, i1 = 2 * tid + 1;
    const int a0 = (i0 < NBKT) ? colsum[i0] : 0;
    const int a1 = (i1 < NBKT) ? colsum[i1] : 0;
    sc[tid] = a0 + a1;
    __syncthreads();
    for (int off = 1; off < 256; off <<= 1) {
        int t = (tid >= off) ? sc[tid - off] : 0;
        __syncthreads();
        sc[tid] += t;
        __syncthreads();
    }
    const int excl = sc[tid] - (a0 + a1);
    if (i0 < NBKT)  sb[i0] = excl;
    if (i1 <= NBKT) sb[i1] = excl + a0;       // writes sb[NBKT] (=total) too
    __syncthreads();
}

// ---------------------------------------------------------------------------
// Launch 1: blocks [0,NB_X) = x -> bf16 convert (streaming, BW-bound; takes
// the f32->bf16 VALU chain OUT of the gemm so its K-loop is load->MFMA);
// block NB_X = W1 swizzled pre-convert; blocks (NB_X, NB_X+NB1] = P1
// bucket-count (LDS histogram, plain stores). No global atomics.
// ---------------------------------------------------------------------------
__global__ __launch_bounds__(256) void k_p1w(
        const int* __restrict__ ei, const float* __restrict__ W1,
        const float* __restrict__ x,
        int* __restrict__ bcnt, ushort* __restrict__ w1b,
        ushort* __restrict__ xb) {
    __shared__ int H[NBKT];
    const int tid = threadIdx.x;
    if (blockIdx.x < NB_X) {                       // ---- x convert ----
        const size_t base = (size_t)blockIdx.x * 8192;
#pragma unroll
        for (int r = 0; r < 8; ++r) {
            const size_t idx = base + (size_t)r * 1024 + tid * 4;
            const float4 v = *(const float4*)(x + idx);
            *(uint2*)(xb + idx) = make_uint2(pk2bf(v.x, v.y), pk2bf(v.z, v.w));
        }
        return;
    }
    if (blockIdx.x == NB_X) {                      // ---- W1 convert ----
        for (int i = 0; i < 64; ++i) {
            const int e = i * 256 + tid;           // e = k*64 + n
            const int k = e >> 6, n = e & 63;
            w1b[((k >> 3) * 64 + n) * 8 + (k & 7)] = f2bf(W1[e]);
        }
        return;
    }
    const int blk = blockIdx.x - NB_X - 1;         // ---- P1 bucket count ----
    for (int j = tid; j < NBKT; j += 256) H[j] = 0;
    __syncthreads();
    const int e0 = blk * EB;
    const int lim = (e0 + EB < N_EDGES) ? e0 + EB : N_EDGES;
    for (int i = e0 + tid; i < lim; i += 256)
        atomicAdd(&H[ei[N_EDGES + i] >> 8], 1);    // LDS atomic
    __syncthreads();
    for (int j = tid; j < NBKT; j += 256)
        bcnt[j * NB1 + blk] = H[j];
}

// ---------------------------------------------------------------------------
// P2: per-bucket exclusive scan of bcnt[bucket][*] across blocks (in place)
// + column sums. One wave per bucket.
// ---------------------------------------------------------------------------
__global__ __launch_bounds__(64) void k_p2(
        int* __restrict__ bcnt, int* __restrict__ colsum) {
    const int col = blockIdx.x, lane = threadIdx.x;
    int carry = 0;
    for (int c0 = 0; c0 < NB1; c0 += 64) {
        const int idx = c0 + lane;
        const int v = (idx < NB1) ? bcnt[col * NB1 + idx] : 0;
        int s = v;
#pragma unroll
        for (int off = 1; off < 64; off <<= 1) {
            int u = __shfl_up(s, off);
            if (lane >= off) s += u;
        }
        if (idx < NB1) bcnt[col * NB1 + idx] = carry + s - v;
        carry += __shfl(s, 63);
    }
    if (lane == 0) colsum[col] = carry;
}

// ---------------------------------------------------------------------------
// P3: bucket scatter. Each block re-reads its EB edges, places PACKED
// (dst&255)<<24 | src into bucket-ordered tmp via LDS cursors.
// ---------------------------------------------------------------------------
__global__ __launch_bounds__(256) void k_p3(
        const int* __restrict__ ei, const int* __restrict__ bcnt,
        const int* __restrict__ colsum, uint* __restrict__ tmp) {
    __shared__ int sc[256];
    __shared__ int cur[NBKT + 1];
    const int tid = threadIdx.x, blk = blockIdx.x;
    bucket_bases(colsum, sc, cur, tid);
    for (int b = tid; b < NBKT; b += 256) cur[b] += bcnt[b * NB1 + blk];
    __syncthreads();
    const int e0 = blk * EB;
    const int lim = (e0 + EB < N_EDGES) ? e0 + EB : N_EDGES;
    for (int i = e0 + tid; i < lim; i += 256) {
        const int s = ei[i], d = ei[N_EDGES + i];
        const int pos = atomicAdd(&cur[d >> 8], 1);     // LDS atomic
        tmp[pos] = ((uint)(d & 255) << 24) | (uint)s;
    }
}

// ---------------------------------------------------------------------------
// Launch 4: blocks [0,NBKT) = final CSR placement; blocks [NBKT,NBKT+NB_G)
// = MFMA gemm (h1 = xb@W1 + s1/d1 dots), A-operand loaded DIRECTLY as
// bf16x8 from pre-converted xb (no per-element f32 convert -> short
// load->MFMA dep chain, low VGPR, loads stay in flight).
// ---------------------------------------------------------------------------
__global__ __launch_bounds__(256) void k_final_gemm(
        const uint* __restrict__ tmp, const int* __restrict__ colsum,
        int* __restrict__ row_ptr, int* __restrict__ srcs,
        const ushort* __restrict__ xb, const ushort* __restrict__ w1b,
        const float* __restrict__ as1, const float* __restrict__ ad1,
        ushort* __restrict__ h1b, float* __restrict__ s1,
        float* __restrict__ d1) {
    __shared__ union {
        struct { int sc[256]; int sb[NBKT + 1]; int cur[BW]; } f;
        ushort B[F_IN * F1];        // 32 KB: W1 bf16 swizzled
        ushort S[4][64][66];        // 33.8 KB: per-wave h staging (pad 66)
    } sm;
    const int tid = threadIdx.x;

    if (blockIdx.x < NBKT) {                       // ---- final placement ----
        const int b = blockIdx.x;
        bucket_bases(colsum, sm.f.sc, sm.f.sb, tid);
        sm.f.cur[tid] = 0;
        __syncthreads();
        const int lo = sm.f.sb[b], hi = sm.f.sb[b + 1];
        for (int i = lo + tid; i < hi; i += 256)
            atomicAdd(&sm.f.cur[tmp[i] >> 24], 1);      // LDS atomic
        __syncthreads();
        const int n = b * BW + tid;
        const int myc = sm.f.cur[tid];
        const int v = (n < N_NODES) ? myc + 1 : 0;      // +1 = self loop
        __syncthreads();
        sm.f.sc[tid] = v;
        __syncthreads();
        for (int off = 1; off < 256; off <<= 1) {
            int t = (tid >= off) ? sm.f.sc[tid - off] : 0;
            __syncthreads();
            sm.f.sc[tid] += t;
            __syncthreads();
        }
        const int rp = lo + b * BW + (sm.f.sc[tid] - v);
        if (n < N_NODES) {
            row_ptr[n] = rp;
            srcs[rp] = n;                               // self loop slot 0
        }
        if (b == NBKT - 1 && tid == 255) row_ptr[N_NODES] = N_TOT;
        sm.f.cur[tid] = rp + 1;                         // edge cursor
        __syncthreads();
        for (int i = lo + tid; i < hi; i += 256) {
            const uint u = tmp[i];
            const int pos = atomicAdd(&sm.f.cur[u >> 24], 1);   // LDS atomic
            srcs[pos] = (int)(u & 0xFFFFFFu);
        }
        return;
    }

    // ---- MFMA gemm part ----
    {   // stage pre-swizzled W1: straight 32 KB vector copy
        const uint4* s4 = (const uint4*)w1b;
        uint4* d4 = (uint4*)sm.B;
#pragma unroll
        for (int i = 0; i < 8; ++i)
            d4[i * 256 + tid] = s4[i * 256 + tid];
    }
    __syncthreads();

    const int wave = tid >> 6, lane = tid & 63;
    const int q = lane >> 4, ln = lane & 15;
    const int rowbase = (blockIdx.x - NBKT) * 256 + wave * 64;

    f32x4 acc[4][4];
#pragma unroll
    for (int mt = 0; mt < 4; ++mt)
#pragma unroll
        for (int nt = 0; nt < 4; ++nt) acc[mt][nt] = (f32x4){0.f, 0.f, 0.f, 0.f};

    const ushort* xrow[4];
#pragma unroll
    for (int mt = 0; mt < 4; ++mt) {
        const int r = rowbase + mt * 16 + ln;
        const int rc = r < N_NODES ? r : N_NODES - 1;
        xrow[mt] = xb + (size_t)rc * F_IN + q * 8;
    }

#pragma unroll 4
    for (int t = 0; t < 8; ++t) {                  // K-loop: 8 x 32
        bf16x8 bfr[4];
#pragma unroll
        for (int nt = 0; nt < 4; ++nt)
            bfr[nt] = *(const bf16x8*)&sm.B[((t * 4 + q) * 64 + nt * 16 + ln) * 8];
        bf16x8 af[4];
#pragma unroll
        for (int mt = 0; mt < 4; ++mt)
            af[mt] = *(const bf16x8*)(xrow[mt] + t * 32);
#pragma unroll
        for (int mt = 0; mt < 4; ++mt)
#pragma unroll
            for (int nt = 0; nt < 4; ++nt)
                acc[mt][nt] = __builtin_amdgcn_mfma_f32_16x16x32_bf16(
                                  af[mt], bfr[nt], acc[mt][nt], 0, 0, 0);
    }
    __syncthreads();

    // stage h (bf16): C/D layout col=lane&15, row=q*4+r
#pragma unroll
    for (int mt = 0; mt < 4; ++mt)
#pragma unroll
        for (int nt = 0; nt < 4; ++nt)
#pragma unroll
            for (int r = 0; r < 4; ++r)
                sm.S[wave][mt * 16 + q * 4 + r][nt * 16 + ln] = f2bf(acc[mt][nt][r]);
    __syncthreads();

    const int node = rowbase + lane;
    if (node >= N_NODES) return;
    const uint* srow = (const uint*)&sm.S[wave][lane][0];
    float sacc[H1], dacc[H1];
#pragma unroll
    for (int h = 0; h < H1; ++h) { sacc[h] = 0.f; dacc[h] = 0.f; }
    uint4* hout = (uint4*)(h1b + (size_t)node * F1);
#pragma unroll
    for (int p4 = 0; p4 < 8; ++p4) {               // p4 == head index
        const uint u0 = srow[p4 * 4 + 0], u1 = srow[p4 * 4 + 1];
        const uint u2 = srow[p4 * 4 + 2], u3 = srow[p4 * 4 + 3];
        hout[p4] = make_uint4(u0, u1, u2, u3);
        const float c[8] = {bflo(u0), bfhi(u0), bflo(u1), bfhi(u1),
                            bflo(u2), bfhi(u2), bflo(u3), bfhi(u3)};
#pragma unroll
        for (int j = 0; j < 8; ++j) {
            sacc[p4] += c[j] * as1[p4 * 8 + j];
            dacc[p4] += c[j] * ad1[p4 * 8 + j];
        }
    }
    float4* s4 = (float4*)(s1 + (size_t)node * H1);
    float4* d4 = (float4*)(d1 + (size_t)node * H1);
    s4[0] = make_float4(sacc[0], sacc[1], sacc[2], sacc[3]);
    s4[1] = make_float4(sacc[4], sacc[5], sacc[6], sacc[7]);
    d4[0] = make_float4(dacc[0], dacc[1], dacc[2], dacc[3]);
    d4[1] = make_float4(dacc[4], dacc[5], dacc[6], dacc[7]);
}

// ---------------------------------------------------------------------------
// K_agg1 (+ fused node GEMM): 8 lanes/edge, lane = head, uint4 h1 loads
// (128B aligned rows; s1 separate 3.2MB = per-XCD L2 resident), f32x2
// accumulators, reduce-scatter epilogue, fused 64x32 W2 GEMM + s2/d2 dots.
// ---------------------------------------------------------------------------
__global__ __launch_bounds__(256) void k_agg1(
        const int* __restrict__ row_ptr, const int* __restrict__ srcs,
        const ushort* __restrict__ h1b, const float* __restrict__ s1,
        const float* __restrict__ d1, const float* __restrict__ b1,
        const float* __restrict__ W2, const float* __restrict__ as2,
        const float* __restrict__ ad2,
        ushort* __restrict__ h2b, float* __restrict__ s2,
        float* __restrict__ d2) {
    __shared__ float sx[4][64];                    // per-wave x2 row (f32)
    const int wid = (blockIdx.x * 256 + threadIdx.x) >> 6;
    if (wid >= N_NODES) return;
    const int w = threadIdx.x >> 6;
    const int lane = threadIdx.x & 63;
    const int q = lane >> 3;          // edge group 0..7
    const int c = lane & 7;           // head (= uint4 idx: channels 8c..8c+7)
    const float dh = d1[(size_t)wid * H1 + c];
    const int beg = row_ptr[wid], end = row_ptr[wid + 1];
    const uint4* hv = (const uint4*)h1b;      // 8 uint4 per node
    f32x2 A0 = {0.f, 0.f}, A1 = {0.f, 0.f}, A2 = {0.f, 0.f}, A3 = {0.f, 0.f};
    float z = 0.f;
    int i = beg + q;
    for (; i + 8 < end; i += 16) {            // edges i, i+8
        const int sA = srcs[i], sB = srcs[i + 8];
        float eA = s1[(size_t)sA * H1 + c] + dh;
        float eB = s1[(size_t)sB * H1 + c] + dh;
        eA = fmaxf(eA, SLOPE * eA);           // leaky (slope<1)
        eB = fmaxf(eB, SLOPE * eB);
        const float xA = __expf(eA), xB = __expf(eB);
        const uint4 UA = hv[(size_t)sA * 8 + c];
        const uint4 UB = hv[(size_t)sB * 8 + c];
        z += xA + xB;
        const f32x2 xa = {xA, xA}, xb2 = {xB, xB};
        A0 += xa * (f32x2){bflo(UA.x), bfhi(UA.x)};
        A1 += xa * (f32x2){bflo(UA.y), bfhi(UA.y)};
        A2 += xa * (f32x2){bflo(UA.z), bfhi(UA.z)};
        A3 += xa * (f32x2){bflo(UA.w), bfhi(UA.w)};
        A0 += xb2 * (f32x2){bflo(UB.x), bfhi(UB.x)};
        A1 += xb2 * (f32x2){bflo(UB.y), bfhi(UB.y)};
        A2 += xb2 * (f32x2){bflo(UB.z), bfhi(UB.z)};
        A3 += xb2 * (f32x2){bflo(UB.w), bfhi(UB.w)};
    }
    for (; i < end; i += 8) {
        const int sA = srcs[i];
        float eA = s1[(size_t)sA * H1 + c] + dh;
        eA = fmaxf(eA, SLOPE * eA);
        const float xA = __expf(eA);
        const uint4 UA = hv[(size_t)sA * 8 + c];
        z += xA;
        const f32x2 xa = {xA, xA};
        A0 += xa * (f32x2){bflo(UA.x), bfhi(UA.x)};
        A1 += xa * (f32x2){bflo(UA.y), bfhi(UA.y)};
        A2 += xa * (f32x2){bflo(UA.z), bfhi(UA.z)};
        A3 += xa * (f32x2){bflo(UA.w), bfhi(UA.w)};
    }
    // ---- reduce-scatter over rep bits 3,4,5: lane ends with channel j ----
    f32x2 r0, r1;
    {   // off=8
        const bool hi = lane & 8;
        f32x2 snd0 = hi ? A0 : A2, snd1 = hi ? A1 : A3;
        const f32x2 kp0 = hi ? A2 : A0, kp1 = hi ? A3 : A1;
        snd0.x = __shfl_xor(snd0.x, 8); snd0.y = __shfl_xor(snd0.y, 8);
        snd1.x = __shfl_xor(snd1.x, 8); snd1.y = __shfl_xor(snd1.y, 8);
        r0 = kp0 + snd0; r1 = kp1 + snd1;
    }
    {   // off=16
        const bool hi = lane & 16;
        f32x2 snd = hi ? r0 : r1;
        const f32x2 kp = hi ? r1 : r0;
        snd.x = __shfl_xor(snd.x, 16); snd.y = __shfl_xor(snd.y, 16);
        r0 = kp + snd;
    }
    float sv;
    {   // off=32
        const bool hi = lane & 32;
        float snd = hi ? r0.x : r0.y;
        const float kp = hi ? r0.y : r0.x;
        snd = __shfl_xor(snd, 32);
        sv = kp + snd;
    }
    z += __shfl_xor(z, 8); z += __shfl_xor(z, 16); z += __shfl_xor(z, 32);

    const int j = (((lane >> 3) & 1) << 2) | (((lane >> 4) & 1) << 1)
                | ((lane >> 5) & 1);
    const int xi = c * 8 + j;                  // this lane's x2 element
    const float zi = 1.f / (z + 1e-16f);
    float xv = sv * zi + b1[xi];
    xv = xv > 0.f ? xv : __expf(xv) - 1.f;     // elu, all 64 lanes (1 each)
    sx[w][xi] = xv;                            // permutation: conflict-free
    __builtin_amdgcn_wave_barrier();           // in-wave LDS RAW ordering

    // fused node GEMM: h2[oc] = sum_k x2[k] * W2[k][oc]  (lane: kh half, oc)
    const int kh = lane >> 5;          // K half 0..1
    const int oc = lane & 31;          // output channel
    const float4* sxv = (const float4*)&sx[w][kh * 32];   // broadcast reads
    const float* wp0 = W2 + (size_t)(kh * 32) * F2 + oc;  // coalesced 128B/half
    float acc = 0.f;
#pragma unroll
    for (int k4 = 0; k4 < 8; ++k4) {
        const float4 xv4 = sxv[k4];
        const float* wp = wp0 + (size_t)k4 * 4 * F2;
        acc += xv4.x * wp[0]      + xv4.y * wp[F2]
             + xv4.z * wp[2 * F2] + xv4.w * wp[3 * F2];
    }
    acc += __shfl_xor(acc, 32);        // combine K halves; all lanes have h2[oc]

    float sA2 = acc * as2[oc], dA2 = acc * ad2[oc];
#pragma unroll
    for (int off = 1; off <= 16; off <<= 1) {
        sA2 += __shfl_xor(sA2, off);
        dA2 += __shfl_xor(dA2, off);
    }
    const float accp = __shfl_xor(acc, 1);     // partner channel (oc^1)
    if (lane < 32 && !(lane & 1))
        *(uint*)&h2b[(size_t)wid * F2 + oc] = pk2bf(acc, accp);
    if (lane == 0) { s2[wid] = sA2; d2[wid] = dA2; }
}

// ---------------------------------------------------------------------------
// K_agg2: 4 lanes/edge (16 groups), uint4 loads, f32x2 accumulators,
// reduce-scatter epilogue -> 1 exp/lane softmax tail. Writes d_out.
// ---------------------------------------------------------------------------
__global__ __launch_bounds__(256) void k_agg2(
        const int* __restrict__ row_ptr, const int* __restrict__ srcs,
        const ushort* __restrict__ h2b, const float* __restrict__ s2,
        const float* __restrict__ d2, const float* __restrict__ b2,
        float* __restrict__ out) {
    const int wid = (blockIdx.x * 256 + threadIdx.x) >> 6;
    if (wid >= N_NODES) return;
    const int lane = threadIdx.x & 63;
    const int q = lane >> 2;          // edge group 0..15
    const int c = lane & 3;           // uint4 idx: channels 8c..8c+7
    const float dn = d2[wid];
    const int beg = row_ptr[wid], end = row_ptr[wid + 1];
    const uint4* hv = (const uint4*)h2b;      // 4 uint4 per node
    f32x2 A0 = {0.f, 0.f}, A1 = {0.f, 0.f}, A2 = {0.f, 0.f}, A3 = {0.f, 0.f};
    float z = 0.f;
    int i = beg + q;
    for (; i + 16 < end; i += 32) {           // edges i, i+16
        const int sA = srcs[i], sB = srcs[i + 16];
        float eA = s2[sA] + dn;
        float eB = s2[sB] + dn;
        eA = fmaxf(eA, SLOPE * eA);
        eB = fmaxf(eB, SLOPE * eB);
        const float xA = __expf(eA), xB = __expf(eB);
        const uint4 UA = hv[(size_t)sA * 4 + c];
        const uint4 UB = hv[(size_t)sB * 4 + c];
        z += xA + xB;
        const f32x2 xa = {xA, xA}, xb2 = {xB, xB};
        A0 += xa * (f32x2){bflo(UA.x), bfhi(UA.x)};
        A1 += xa * (f32x2){bflo(UA.y), bfhi(UA.y)};
        A2 += xa * (f32x2){bflo(UA.z), bfhi(UA.z)};
        A3 += xa * (f32x2){bflo(UA.w), bfhi(UA.w)};
        A0 += xb2 * (f32x2){bflo(UB.x), bfhi(UB.x)};
        A1 += xb2 * (f32x2){bflo(UB.y), bfhi(UB.y)};
        A2 += xb2 * (f32x2){bflo(UB.z), bfhi(UB.z)};
        A3 += xb2 * (f32x2){bflo(UB.w), bfhi(UB.w)};
    }
    for (; i < end; i += 16) {
        const int sA = srcs[i];
        float eA = s2[sA] + dn;
        eA = fmaxf(eA, SLOPE * eA);
        const float xA = __expf(eA);
        const uint4 UA = hv[(size_t)sA * 4 + c];
        z += xA;
        const f32x2 xa = {xA, xA};
        A0 += xa * (f32x2){bflo(UA.x), bfhi(UA.x)};
        A1 += xa * (f32x2){bflo(UA.y), bfhi(UA.y)};
        A2 += xa * (f32x2){bflo(UA.z), bfhi(UA.z)};
        A3 += xa * (f32x2){bflo(UA.w), bfhi(UA.w)};
    }
    // ---- reduce-scatter over rep bits 2,3,4; plain combine over bit5 ----
    f32x2 r0, r1;
    {
        const bool hi = lane & 4;
        f32x2 snd0 = hi ? A0 : A2, snd1 = hi ? A1 : A3;
        const f32x2 kp0 = hi ? A2 : A0, kp1 = hi ? A3 : A1;
        snd0.x = __shfl_xor(snd0.x, 4); snd0.y = __shfl_xor(snd0.y, 4);
        snd1.x = __shfl_xor(snd1.x, 4); snd1.y = __shfl_xor(snd1.y, 4);
        r0 = kp0 + snd0; r1 = kp1 + snd1;
    }
    {
        const bool hi = lane & 8;
        f32x2 snd = hi ? r0 : r1;
        const f32x2 kp = hi ? r1 : r0;
        snd.x = __shfl_xor(snd.x, 8); snd.y = __shfl_xor(snd.y, 8);
        r0 = kp + snd;
    }
    float sv;
    {
        const bool hi = lane & 16;
        float snd = hi ? r0.x : r0.y;
        const float kp = hi ? r0.y : r0.x;
        snd = __shfl_xor(snd, 16);
        sv = kp + snd;
    }
    sv += __shfl_xor(sv, 32);          // lanes l, l^32 now duplicate
    z += __shfl_xor(z, 4); z += __shfl_xor(z, 8);
    z += __shfl_xor(z, 16); z += __shfl_xor(z, 32);

    const int j = (((lane >> 2) & 1) << 2) | (((lane >> 3) & 1) << 1)
                | ((lane >> 4) & 1);
    const int elem = c * 8 + j;        // this lane's class (dup over bit5)
    const float zi = 1.f / (z + 1e-16f);
    const float v = sv * zi + b2[elem];
    // log-softmax over the 32 classes: each 32-lane half holds all 32 once.
    float m = v;
#pragma unroll
    for (int off = 1; off <= 16; off <<= 1) m = fmaxf(m, __shfl_xor(m, off));
    float ssum = __expf(v - m);
#pragma unroll
    for (int off = 1; off <= 16; off <<= 1) ssum += __shfl_xor(ssum, off);
    const float lse = m + __logf(ssum);
    if (lane < 32) out[(size_t)wid * F2 + elem] = v - lse;
}

extern "C" void kernel_launch(void* const* d_in, const int* in_sizes, int n_in,
                              void* d_out, int out_size, void* d_ws, size_t ws_size,
                              hipStream_t stream) {
    const float* x   = (const float*)d_in[0];
    const int*   ei  = (const int*)d_in[1];
    const float* W1  = (const float*)d_in[2];
    const float* as1 = (const float*)d_in[3];
    const float* ad1 = (const float*)d_in[4];
    const float* b1  = (const float*)d_in[5];
    const float* W2  = (const float*)d_in[6];
    const float* as2 = (const float*)d_in[7];
    const float* ad2 = (const float*)d_in[8];
    const float* b2  = (const float*)d_in[9];
    float* out = (float*)d_out;

    // Workspace layout
    ushort* xb  = (ushort*)d_ws;                   // N*256 bf16 (51.2 MB)
    ushort* h1b = xb + (size_t)N_NODES * F_IN;     // N*64 bf16 (128B rows)
    ushort* h2b = h1b + (size_t)N_NODES * F1;      // N*32 bf16
    ushort* w1b = h2b + (size_t)N_NODES * F2;      // 16384 bf16 (swizzled W1)
    float*  s1  = (float*)(w1b + F_IN * F1);       // N*8
    float*  d1  = s1 + (size_t)N_NODES * H1;       // N*8
    float*  s2  = d1 + (size_t)N_NODES * H1;       // N
    float*  d2  = s2 + N_NODES;                    // N
    uint*   tmp = (uint*)(d2 + N_NODES);           // N_EDGES (packed)
    int* row_ptr = (int*)(tmp + N_EDGES);          // N+1
    int* colsum  = row_ptr + N_NODES + 1;          // NBKT
    int* bcnt    = colsum + NBKT;                  // NBKT*NB1
    int* srcs    = bcnt + (size_t)NBKT * NB1;      // N_TOT

    const int nb_w = (N_NODES * 64 + 255) / 256;   // one wave per node

    k_p1w<<<NB_X + 1 + NB1, 256, 0, stream>>>(ei, W1, x, bcnt, w1b, xb);
    k_p2<<<NBKT, 64, 0, stream>>>(bcnt, colsum);
    k_p3<<<NB1, 256, 0, stream>>>(ei, bcnt, colsum, tmp);
    k_final_gemm<<<NBKT + NB_G, 256, 0, stream>>>(tmp, colsum, row_ptr, srcs,
                                                  xb, w1b, as1, ad1,
                                                  h1b, s1, d1);
    k_agg1<<<nb_w, 256, 0, stream>>>(row_ptr, srcs, h1b, s1, d1, b1,
                                     W2, as2, ad2, h2b, s2, d2);
    k_agg2<<<nb_w, 256, 0, stream>>>(row_ptr, srcs, h2b, s2, d2, b2, out);
}

// Round 8
// 344.982 us; speedup vs baseline: 1.0271x; 1.0077x over previous
//
#include <hip/hip_runtime.h>
#include <hip/hip_bf16.h>

#define N_NODES 100000
#define N_EDGES 1600000
#define N_TOT   (N_EDGES + N_NODES)   // edges + self loops
#define F_IN    256
#define F1      64     // H1*C1
#define H1      8
#define C1      8
#define F2      32
#define SLOPE   0.2f

#define NB_G    ((N_NODES + 255) / 256)           // 391 gemm blocks
#define NB_X    3125                               // x->bf16 convert blocks (25.6e6/8192)

// counting-sort CSR build (no global atomics)
#define EB      4096                               // edges per P1/P3 block
#define NB1     ((N_EDGES + EB - 1) / EB)          // 391
#define BW      256                                // nodes per bucket
#define NBKT    ((N_NODES + BW - 1) / BW)          // 391

typedef unsigned int  uint;
typedef unsigned short ushort;
typedef __attribute__((ext_vector_type(8))) short bf16x8;
typedef __attribute__((ext_vector_type(4))) float f32x4;
typedef __attribute__((ext_vector_type(2))) float f32x2;

__device__ inline ushort f2bf(float f) {               // RNE float->bf16
    uint u = __float_as_uint(f);
    uint r = u + 0x7fffu + ((u >> 16) & 1u);
    return (ushort)(r >> 16);
}
__device__ inline float bflo(uint u) { return __uint_as_float(u << 16); }
__device__ inline float bfhi(uint u) { return __uint_as_float(u & 0xffff0000u); }
__device__ inline uint pk2bf(float a, float b) {
    __hip_bfloat162 h = __float22bfloat162_rn(make_float2(a, b));
    union { __hip_bfloat162 h; uint u; } cv; cv.h = h;
    return cv.u;
}

// Block-wide exclusive scan of colsum[NBKT] -> sb[0..NBKT] (sb[NBKT]=total).
__device__ inline void bucket_bases(const int* __restrict__ colsum,
                                    int* sc, int* sb, int tid) {
    const int i0 = 2 * tid, i1 = 2 * tid + 1;
    const int a0 = (i0 < NBKT) ? colsum[i0] : 0;
    const int a1 = (i1 < NBKT) ? colsum[i1] : 0;
    sc[tid] = a0 + a1;
    __syncthreads();
    for (int off = 1; off < 256; off <<= 1) {
        int t = (tid >= off) ? sc[tid - off] : 0;
        __syncthreads();
        sc[tid] += t;
        __syncthreads();
    }
    const int excl = sc[tid] - (a0 + a1);
    if (i0 < NBKT)  sb[i0] = excl;
    if (i1 <= NBKT) sb[i1] = excl + a0;       // writes sb[NBKT] (=total) too
    __syncthreads();
}

// ---------------------------------------------------------------------------
// Launch 1: blocks [0,NB_X) = x -> bf16 convert (streaming, BW-bound);
// block NB_X = W1 swizzled pre-convert; blocks (NB_X, NB_X+NB1] = P1
// bucket-count (LDS histogram, int2 edge loads, plain stores to bcnt).
// ---------------------------------------------------------------------------
__global__ __launch_bounds__(256) void k_p1w(
        const int* __restrict__ ei, const float* __restrict__ W1,
        const float* __restrict__ x,
        int* __restrict__ bcnt, ushort* __restrict__ w1b,
        ushort* __restrict__ xb) {
    __shared__ int H[NBKT];
    const int tid = threadIdx.x;
    if (blockIdx.x < NB_X) {                       // ---- x convert ----
        const size_t base = (size_t)blockIdx.x * 8192;
#pragma unroll
        for (int r = 0; r < 8; ++r) {
            const size_t idx = base + (size_t)r * 1024 + tid * 4;
            const float4 v = *(const float4*)(x + idx);
            *(uint2*)(xb + idx) = make_uint2(pk2bf(v.x, v.y), pk2bf(v.z, v.w));
        }
        return;
    }
    if (blockIdx.x == NB_X) {                      // ---- W1 convert ----
        for (int i = 0; i < 64; ++i) {
            const int e = i * 256 + tid;           // e = k*64 + n
            const int k = e >> 6, n = e & 63;
            w1b[((k >> 3) * 64 + n) * 8 + (k & 7)] = f2bf(W1[e]);
        }
        return;
    }
    const int blk = blockIdx.x - NB_X - 1;         // ---- P1 bucket count ----
    for (int j = tid; j < NBKT; j += 256) H[j] = 0;
    __syncthreads();
    const int e0 = blk * EB;
    const int lim = (e0 + EB < N_EDGES) ? e0 + EB : N_EDGES;
    for (int i = e0 + tid * 2; i < lim; i += 512) {    // (lim-e0) % 512 == 0
        const int2 dd = *(const int2*)&ei[N_EDGES + i];
        atomicAdd(&H[dd.x >> 8], 1);               // LDS atomic
        atomicAdd(&H[dd.y >> 8], 1);
    }
    __syncthreads();
    for (int j = tid; j < NBKT; j += 256)
        bcnt[j * NB1 + blk] = H[j];
}

// ---------------------------------------------------------------------------
// P2: per-bucket exclusive scan of bcnt[bucket][*] across blocks (in place)
// + column sums. One wave per bucket.
// ---------------------------------------------------------------------------
__global__ __launch_bounds__(64) void k_p2(
        int* __restrict__ bcnt, int* __restrict__ colsum) {
    const int col = blockIdx.x, lane = threadIdx.x;
    int carry = 0;
    for (int c0 = 0; c0 < NB1; c0 += 64) {
        const int idx = c0 + lane;
        const int v = (idx < NB1) ? bcnt[col * NB1 + idx] : 0;
        int s = v;
#pragma unroll
        for (int off = 1; off < 64; off <<= 1) {
            int u = __shfl_up(s, off);
            if (lane >= off) s += u;
        }
        if (idx < NB1) bcnt[col * NB1 + idx] = carry + s - v;
        carry += __shfl(s, 63);
    }
    if (lane == 0) colsum[col] = carry;
}

// ---------------------------------------------------------------------------
// P3: bucket scatter. int2-vectorized edge loads; places PACKED
// (dst&255)<<24 | src into bucket-ordered tmp via LDS cursors.
// ---------------------------------------------------------------------------
__global__ __launch_bounds__(256) void k_p3(
        const int* __restrict__ ei, const int* __restrict__ bcnt,
        const int* __restrict__ colsum, uint* __restrict__ tmp) {
    __shared__ int sc[256];
    __shared__ int cur[NBKT + 1];
    const int tid = threadIdx.x, blk = blockIdx.x;
    bucket_bases(colsum, sc, cur, tid);
    for (int b = tid; b < NBKT; b += 256) cur[b] += bcnt[b * NB1 + blk];
    __syncthreads();
    const int e0 = blk * EB;
    const int lim = (e0 + EB < N_EDGES) ? e0 + EB : N_EDGES;
    for (int i = e0 + tid * 2; i < lim; i += 512) {    // (lim-e0) % 512 == 0
        const int2 ss = *(const int2*)&ei[i];
        const int2 dd = *(const int2*)&ei[N_EDGES + i];
        const int p0 = atomicAdd(&cur[dd.x >> 8], 1);  // LDS atomic
        tmp[p0] = ((uint)(dd.x & 255) << 24) | (uint)ss.x;
        const int p1 = atomicAdd(&cur[dd.y >> 8], 1);
        tmp[p1] = ((uint)(dd.y & 255) << 24) | (uint)ss.y;
    }
}

// ---------------------------------------------------------------------------
// Launch 4: blocks [0,NBKT) = final CSR placement; blocks [NBKT,NBKT+NB_G)
// = MFMA gemm (h1 = xb@W1 + s1/d1 dots), A-operand loaded directly as
// bf16x8 from pre-converted xb.
// ---------------------------------------------------------------------------
__global__ __launch_bounds__(256) void k_final_gemm(
        const uint* __restrict__ tmp, const int* __restrict__ colsum,
        int* __restrict__ row_ptr, int* __restrict__ srcs,
        const ushort* __restrict__ xb, const ushort* __restrict__ w1b,
        const float* __restrict__ as1, const float* __restrict__ ad1,
        ushort* __restrict__ h1b, float* __restrict__ s1,
        float* __restrict__ d1) {
    __shared__ union {
        struct { int sc[256]; int sb[NBKT + 1]; int cur[BW]; } f;
        ushort B[F_IN * F1];        // 32 KB: W1 bf16 swizzled
        ushort S[4][64][66];        // 33.8 KB: per-wave h staging (pad 66)
    } sm;
    const int tid = threadIdx.x;

    if (blockIdx.x < NBKT) {                       // ---- final placement ----
        const int b = blockIdx.x;
        bucket_bases(colsum, sm.f.sc, sm.f.sb, tid);
        sm.f.cur[tid] = 0;
        __syncthreads();
        const int lo = sm.f.sb[b], hi = sm.f.sb[b + 1];
        for (int i = lo + tid; i < hi; i += 256)
            atomicAdd(&sm.f.cur[tmp[i] >> 24], 1);      // LDS atomic
        __syncthreads();
        const int n = b * BW + tid;
        const int myc = sm.f.cur[tid];
        const int v = (n < N_NODES) ? myc + 1 : 0;      // +1 = self loop
        __syncthreads();
        sm.f.sc[tid] = v;
        __syncthreads();
        for (int off = 1; off < 256; off <<= 1) {
            int t = (tid >= off) ? sm.f.sc[tid - off] : 0;
            __syncthreads();
            sm.f.sc[tid] += t;
            __syncthreads();
        }
        const int rp = lo + b * BW + (sm.f.sc[tid] - v);
        if (n < N_NODES) {
            row_ptr[n] = rp;
            srcs[rp] = n;                               // self loop slot 0
        }
        if (b == NBKT - 1 && tid == 255) row_ptr[N_NODES] = N_TOT;
        sm.f.cur[tid] = rp + 1;                         // edge cursor
        __syncthreads();
        for (int i = lo + tid; i < hi; i += 256) {
            const uint u = tmp[i];
            const int pos = atomicAdd(&sm.f.cur[u >> 24], 1);   // LDS atomic
            srcs[pos] = (int)(u & 0xFFFFFFu);
        }
        return;
    }

    // ---- MFMA gemm part ----
    {   // stage pre-swizzled W1: straight 32 KB vector copy
        const uint4* s4 = (const uint4*)w1b;
        uint4* d4 = (uint4*)sm.B;
#pragma unroll
        for (int i = 0; i < 8; ++i)
            d4[i * 256 + tid] = s4[i * 256 + tid];
    }
    __syncthreads();

    const int wave = tid >> 6, lane = tid & 63;
    const int q = lane >> 4, ln = lane & 15;
    const int rowbase = (blockIdx.x - NBKT) * 256 + wave * 64;

    f32x4 acc[4][4];
#pragma unroll
    for (int mt = 0; mt < 4; ++mt)
#pragma unroll
        for (int nt = 0; nt < 4; ++nt) acc[mt][nt] = (f32x4){0.f, 0.f, 0.f, 0.f};

    const ushort* xrow[4];
#pragma unroll
    for (int mt = 0; mt < 4; ++mt) {
        const int r = rowbase + mt * 16 + ln;
        const int rc = r < N_NODES ? r : N_NODES - 1;
        xrow[mt] = xb + (size_t)rc * F_IN + q * 8;
    }

#pragma unroll 4
    for (int t = 0; t < 8; ++t) {                  // K-loop: 8 x 32
        bf16x8 bfr[4];
#pragma unroll
        for (int nt = 0; nt < 4; ++nt)
            bfr[nt] = *(const bf16x8*)&sm.B[((t * 4 + q) * 64 + nt * 16 + ln) * 8];
        bf16x8 af[4];
#pragma unroll
        for (int mt = 0; mt < 4; ++mt)
            af[mt] = *(const bf16x8*)(xrow[mt] + t * 32);
#pragma unroll
        for (int mt = 0; mt < 4; ++mt)
#pragma unroll
            for (int nt = 0; nt < 4; ++nt)
                acc[mt][nt] = __builtin_amdgcn_mfma_f32_16x16x32_bf16(
                                  af[mt], bfr[nt], acc[mt][nt], 0, 0, 0);
    }
    __syncthreads();

    // stage h (bf16): C/D layout col=lane&15, row=q*4+r
#pragma unroll
    for (int mt = 0; mt < 4; ++mt)
#pragma unroll
        for (int nt = 0; nt < 4; ++nt)
#pragma unroll
            for (int r = 0; r < 4; ++r)
                sm.S[wave][mt * 16 + q * 4 + r][nt * 16 + ln] = f2bf(acc[mt][nt][r]);
    __syncthreads();

    const int node = rowbase + lane;
    if (node >= N_NODES) return;
    const uint* srow = (const uint*)&sm.S[wave][lane][0];
    float sacc[H1], dacc[H1];
#pragma unroll
    for (int h = 0; h < H1; ++h) { sacc[h] = 0.f; dacc[h] = 0.f; }
    uint4* hout = (uint4*)(h1b + (size_t)node * F1);
#pragma unroll
    for (int p4 = 0; p4 < 8; ++p4) {               // p4 == head index
        const uint u0 = srow[p4 * 4 + 0], u1 = srow[p4 * 4 + 1];
        const uint u2 = srow[p4 * 4 + 2], u3 = srow[p4 * 4 + 3];
        hout[p4] = make_uint4(u0, u1, u2, u3);
        const float c[8] = {bflo(u0), bfhi(u0), bflo(u1), bfhi(u1),
                            bflo(u2), bfhi(u2), bflo(u3), bfhi(u3)};
#pragma unroll
        for (int j = 0; j < 8; ++j) {
            sacc[p4] += c[j] * as1[p4 * 8 + j];
            dacc[p4] += c[j] * ad1[p4 * 8 + j];
        }
    }
    float4* s4 = (float4*)(s1 + (size_t)node * H1);
    float4* d4 = (float4*)(d1 + (size_t)node * H1);
    s4[0] = make_float4(sacc[0], sacc[1], sacc[2], sacc[3]);
    s4[1] = make_float4(sacc[4], sacc[5], sacc[6], sacc[7]);
    d4[0] = make_float4(dacc[0], dacc[1], dacc[2], dacc[3]);
    d4[1] = make_float4(dacc[4], dacc[5], dacc[6], dacc[7]);
}

// ---------------------------------------------------------------------------
// K_agg1 (+ fused node GEMM): 8 lanes/edge, lane = head. Gathers use
// 32-bit byte offsets off char* bases (saddr-form loads: 1 u24-mad per
// address instead of a 64-bit mad/shift/addc chain). f32x2 accumulators,
// reduce-scatter epilogue, fused 64x32 W2 GEMM + s2/d2 dots.
// ---------------------------------------------------------------------------
__global__ __launch_bounds__(256) void k_agg1(
        const int* __restrict__ row_ptr, const int* __restrict__ srcs,
        const ushort* __restrict__ h1b, const float* __restrict__ s1,
        const float* __restrict__ d1, const float* __restrict__ b1,
        const float* __restrict__ W2, const float* __restrict__ as2,
        const float* __restrict__ ad2,
        ushort* __restrict__ h2b, float* __restrict__ s2,
        float* __restrict__ d2) {
    __shared__ float sx[4][64];                    // per-wave x2 row (f32)
    const int wid = (blockIdx.x * 256 + threadIdx.x) >> 6;
    if (wid >= N_NODES) return;
    const int w = threadIdx.x >> 6;
    const int lane = threadIdx.x & 63;
    const int q = lane >> 3;          // edge group 0..7
    const int c = lane & 7;           // head (= uint4 idx: channels 8c..8c+7)
    const float dh = d1[(size_t)wid * H1 + c];
    const int beg = row_ptr[wid], end = row_ptr[wid + 1];
    const char* hP = (const char*)h1b;        // 128B rows, 12.8 MB
    const char* sP = (const char*)s1;         // 32B rows, 3.2 MB
    const uint hc16 = 16u * (uint)c;
    const uint sc4 = 4u * (uint)c;
    f32x2 A0 = {0.f, 0.f}, A1 = {0.f, 0.f}, A2 = {0.f, 0.f}, A3 = {0.f, 0.f};
    float z = 0.f;
    int i = beg + q;
    for (; i + 8 < end; i += 16) {            // edges i, i+8
        const int nA = srcs[i], nB = srcs[i + 8];
        float eA = *(const float*)(sP + ((uint)nA * 32u + sc4)) + dh;
        float eB = *(const float*)(sP + ((uint)nB * 32u + sc4)) + dh;
        eA = fmaxf(eA, SLOPE * eA);           // leaky (slope<1)
        eB = fmaxf(eB, SLOPE * eB);
        const float xA = __expf(eA), xB = __expf(eB);
        const uint4 UA = *(const uint4*)(hP + ((uint)nA * 128u + hc16));
        const uint4 UB = *(const uint4*)(hP + ((uint)nB * 128u + hc16));
        z += xA + xB;
        const f32x2 xa = {xA, xA}, xb2 = {xB, xB};
        A0 += xa * (f32x2){bflo(UA.x), bfhi(UA.x)};
        A1 += xa * (f32x2){bflo(UA.y), bfhi(UA.y)};
        A2 += xa * (f32x2){bflo(UA.z), bfhi(UA.z)};
        A3 += xa * (f32x2){bflo(UA.w), bfhi(UA.w)};
        A0 += xb2 * (f32x2){bflo(UB.x), bfhi(UB.x)};
        A1 += xb2 * (f32x2){bflo(UB.y), bfhi(UB.y)};
        A2 += xb2 * (f32x2){bflo(UB.z), bfhi(UB.z)};
        A3 += xb2 * (f32x2){bflo(UB.w), bfhi(UB.w)};
    }
    for (; i < end; i += 8) {
        const int nA = srcs[i];
        float eA = *(const float*)(sP + ((uint)nA * 32u + sc4)) + dh;
        eA = fmaxf(eA, SLOPE * eA);
        const float xA = __expf(eA);
        const uint4 UA = *(const uint4*)(hP + ((uint)nA * 128u + hc16));
        z += xA;
        const f32x2 xa = {xA, xA};
        A0 += xa * (f32x2){bflo(UA.x), bfhi(UA.x)};
        A1 += xa * (f32x2){bflo(UA.y), bfhi(UA.y)};
        A2 += xa * (f32x2){bflo(UA.z), bfhi(UA.z)};
        A3 += xa * (f32x2){bflo(UA.w), bfhi(UA.w)};
    }
    // ---- reduce-scatter over rep bits 3,4,5: lane ends with channel j ----
    f32x2 r0, r1;
    {   // off=8
        const bool hi = lane & 8;
        f32x2 snd0 = hi ? A0 : A2, snd1 = hi ? A1 : A3;
        const f32x2 kp0 = hi ? A2 : A0, kp1 = hi ? A3 : A1;
        snd0.x = __shfl_xor(snd0.x, 8); snd0.y = __shfl_xor(snd0.y, 8);
        snd1.x = __shfl_xor(snd1.x, 8); snd1.y = __shfl_xor(snd1.y, 8);
        r0 = kp0 + snd0; r1 = kp1 + snd1;
    }
    {   // off=16
        const bool hi = lane & 16;
        f32x2 snd = hi ? r0 : r1;
        const f32x2 kp = hi ? r1 : r0;
        snd.x = __shfl_xor(snd.x, 16); snd.y = __shfl_xor(snd.y, 16);
        r0 = kp + snd;
    }
    float sv;
    {   // off=32
        const bool hi = lane & 32;
        float snd = hi ? r0.x : r0.y;
        const float kp = hi ? r0.y : r0.x;
        snd = __shfl_xor(snd, 32);
        sv = kp + snd;
    }
    z += __shfl_xor(z, 8); z += __shfl_xor(z, 16); z += __shfl_xor(z, 32);

    const int j = (((lane >> 3) & 1) << 2) | (((lane >> 4) & 1) << 1)
                | ((lane >> 5) & 1);
    const int xi = c * 8 + j;                  // this lane's x2 element
    const float zi = 1.f / (z + 1e-16f);
    float xv = sv * zi + b1[xi];
    xv = xv > 0.f ? xv : __expf(xv) - 1.f;     // elu, all 64 lanes (1 each)
    sx[w][xi] = xv;                            // permutation: conflict-free
    __builtin_amdgcn_wave_barrier();           // in-wave LDS RAW ordering

    // fused node GEMM: h2[oc] = sum_k x2[k] * W2[k][oc]  (lane: kh half, oc)
    const int kh = lane >> 5;          // K half 0..1
    const int oc = lane & 31;          // output channel
    const float4* sxv = (const float4*)&sx[w][kh * 32];   // broadcast reads
    const float* wp0 = W2 + (size_t)(kh * 32) * F2 + oc;  // coalesced 128B/half
    float acc = 0.f;
#pragma unroll
    for (int k4 = 0; k4 < 8; ++k4) {
        const float4 xv4 = sxv[k4];
        const float* wp = wp0 + (size_t)k4 * 4 * F2;
        acc += xv4.x * wp[0]      + xv4.y * wp[F2]
             + xv4.z * wp[2 * F2] + xv4.w * wp[3 * F2];
    }
    acc += __shfl_xor(acc, 32);        // combine K halves; all lanes have h2[oc]

    float sA2 = acc * as2[oc], dA2 = acc * ad2[oc];
#pragma unroll
    for (int off = 1; off <= 16; off <<= 1) {
        sA2 += __shfl_xor(sA2, off);
        dA2 += __shfl_xor(dA2, off);
    }
    const float accp = __shfl_xor(acc, 1);     // partner channel (oc^1)
    if (lane < 32 && !(lane & 1))
        *(uint*)&h2b[(size_t)wid * F2 + oc] = pk2bf(acc, accp);
    if (lane == 0) { s2[wid] = sA2; d2[wid] = dA2; }
}

// ---------------------------------------------------------------------------
// K_agg2: 2 lanes/edge (32 groups; lane bit0 = channel half, 2x uint4 per
// lane) -> exp/address work per edge halved vs 4-lane; a deg-17 node needs
// ONE loop iteration. Reduce-scatter over bits 1-4 (+ combine over bit 5)
// leaves each lane one class logit; 1 exp/lane softmax tail. Writes d_out.
// ---------------------------------------------------------------------------
__global__ __launch_bounds__(256) void k_agg2(
        const int* __restrict__ row_ptr, const int* __restrict__ srcs,
        const ushort* __restrict__ h2b, const float* __restrict__ s2,
        const float* __restrict__ d2, const float* __restrict__ b2,
        float* __restrict__ out) {
    const int wid = (blockIdx.x * 256 + threadIdx.x) >> 6;
    if (wid >= N_NODES) return;
    const int lane = threadIdx.x & 63;
    const int q = lane >> 1;          // edge group 0..31
    const int ch = lane & 1;          // channel half: channels 16ch..16ch+15
    const float dn = d2[wid];
    const int beg = row_ptr[wid], end = row_ptr[wid + 1];
    const char* hP = (const char*)h2b;        // 64B rows, 6.4 MB
    const char* sP = (const char*)s2;         // 4B, 0.4 MB
    const uint ch32 = 32u * (uint)ch;
    f32x2 A0 = {0.f, 0.f}, A1 = {0.f, 0.f}, A2 = {0.f, 0.f}, A3 = {0.f, 0.f};
    f32x2 A4 = {0.f, 0.f}, A5 = {0.f, 0.f}, A6 = {0.f, 0.f}, A7 = {0.f, 0.f};
    float z = 0.f;
    for (int i = beg + q; i < end; i += 32) {
        const int nA = srcs[i];
        float eA = *(const float*)(sP + (uint)nA * 4u) + dn;
        eA = fmaxf(eA, SLOPE * eA);
        const float xA = __expf(eA);
        const uint off = (uint)nA * 64u + ch32;
        const uint4 U0 = *(const uint4*)(hP + off);
        const uint4 U1 = *(const uint4*)(hP + off + 16);
        z += xA;
        const f32x2 xa = {xA, xA};
        A0 += xa * (f32x2){bflo(U0.x), bfhi(U0.x)};
        A1 += xa * (f32x2){bflo(U0.y), bfhi(U0.y)};
        A2 += xa * (f32x2){bflo(U0.z), bfhi(U0.z)};
        A3 += xa * (f32x2){bflo(U0.w), bfhi(U0.w)};
        A4 += xa * (f32x2){bflo(U1.x), bfhi(U1.x)};
        A5 += xa * (f32x2){bflo(U1.y), bfhi(U1.y)};
        A6 += xa * (f32x2){bflo(U1.z), bfhi(U1.z)};
        A7 += xa * (f32x2){bflo(U1.w), bfhi(U1.w)};
    }
    // ---- reduce-scatter over bits 1,2,3,4; plain combine over bit 5 ----
    f32x2 r0, r1, r2, r3;
    {   // off=2 (bit1 -> rel-ch bit3): 8 -> 4
        const bool hi = lane & 2;
        f32x2 s0 = hi ? A0 : A4, s1v = hi ? A1 : A5;
        f32x2 s2v = hi ? A2 : A6, s3v = hi ? A3 : A7;
        const f32x2 k0 = hi ? A4 : A0, k1 = hi ? A5 : A1;
        const f32x2 k2 = hi ? A6 : A2, k3 = hi ? A7 : A3;
        s0.x = __shfl_xor(s0.x, 2); s0.y = __shfl_xor(s0.y, 2);
        s1v.x = __shfl_xor(s1v.x, 2); s1v.y = __shfl_xor(s1v.y, 2);
        s2v.x = __shfl_xor(s2v.x, 2); s2v.y = __shfl_xor(s2v.y, 2);
        s3v.x = __shfl_xor(s3v.x, 2); s3v.y = __shfl_xor(s3v.y, 2);
        r0 = k0 + s0; r1 = k1 + s1v; r2 = k2 + s2v; r3 = k3 + s3v;
    }
    {   // off=4 (bit2 -> rel-ch bit2): 4 -> 2
        const bool hi = lane & 4;
        f32x2 s0 = hi ? r0 : r2, s1v = hi ? r1 : r3;
        const f32x2 k0 = hi ? r2 : r0, k1 = hi ? r3 : r1;
        s0.x = __shfl_xor(s0.x, 4); s0.y = __shfl_xor(s0.y, 4);
        s1v.x = __shfl_xor(s1v.x, 4); s1v.y = __shfl_xor(s1v.y, 4);
        r0 = k0 + s0; r1 = k1 + s1v;
    }
    {   // off=8 (bit3 -> rel-ch bit1): 2 -> 1
        const bool hi = lane & 8;
        f32x2 s0 = hi ? r0 : r1;
        const f32x2 k0 = hi ? r1 : r0;
        s0.x = __shfl_xor(s0.x, 8); s0.y = __shfl_xor(s0.y, 8);
        r0 = k0 + s0;
    }
    float sv;
    {   // off=16 (bit4 -> rel-ch bit0): f32x2 -> float
        const bool hi = lane & 16;
        float s0 = hi ? r0.x : r0.y;
        const float k0 = hi ? r0.y : r0.x;
        s0 = __shfl_xor(s0, 16);
        sv = k0 + s0;
    }
    sv += __shfl_xor(sv, 32);          // lanes l, l^32 now duplicate
    z += __shfl_xor(z, 2); z += __shfl_xor(z, 4); z += __shfl_xor(z, 8);
    z += __shfl_xor(z, 16); z += __shfl_xor(z, 32);

    const int elem = ch * 16 + (((lane >> 1) & 1) << 3) | (((lane >> 2) & 1) << 2)
                   | (((lane >> 3) & 1) << 1) | ((lane >> 4) & 1);
    const float zi = 1.f / (z + 1e-16f);
    const float v = sv * zi + b2[elem];
    // log-softmax over the 32 classes: each 32-lane half holds all 32 once.
    float m = v;
#pragma unroll
    for (int off = 1; off <= 16; off <<= 1) m = fmaxf(m, __shfl_xor(m, off));
    float ssum = __expf(v - m);
#pragma unroll
    for (int off = 1; off <= 16; off <<= 1) ssum += __shfl_xor(ssum, off);
    const float lse = m + __logf(ssum);
    if (lane < 32) out[(size_t)wid * F2 + elem] = v - lse;
}

extern "C" void kernel_launch(void* const* d_in, const int* in_sizes, int n_in,
                              void* d_out, int out_size, void* d_ws, size_t ws_size,
                              hipStream_t stream) {
    const float* x   = (const float*)d_in[0];
    const int*   ei  = (const int*)d_in[1];
    const float* W1  = (const float*)d_in[2];
    const float* as1 = (const float*)d_in[3];
    const float* ad1 = (const float*)d_in[4];
    const float* b1  = (const float*)d_in[5];
    const float* W2  = (const float*)d_in[6];
    const float* as2 = (const float*)d_in[7];
    const float* ad2 = (const float*)d_in[8];
    const float* b2  = (const float*)d_in[9];
    float* out = (float*)d_out;

    // Workspace layout
    ushort* xb  = (ushort*)d_ws;                   // N*256 bf16 (51.2 MB)
    ushort* h1b = xb + (size_t)N_NODES * F_IN;     // N*64 bf16 (128B rows)
    ushort* h2b = h1b + (size_t)N_NODES * F1;      // N*32 bf16
    ushort* w1b = h2b + (size_t)N_NODES * F2;      // 16384 bf16 (swizzled W1)
    float*  s1  = (float*)(w1b + F_IN * F1);       // N*8
    float*  d1  = s1 + (size_t)N_NODES * H1;       // N*8
    float*  s2  = d1 + (size_t)N_NODES * H1;       // N
    float*  d2  = s2 + N_NODES;                    // N
    uint*   tmp = (uint*)(d2 + N_NODES);           // N_EDGES (packed)
    int* row_ptr = (int*)(tmp + N_EDGES);          // N+1
    int* colsum  = row_ptr + N_NODES + 1;          // NBKT
    int* bcnt    = colsum + NBKT;                  // NBKT*NB1
    int* srcs    = bcnt + (size_t)NBKT * NB1;      // N_TOT

    const int nb_w = (N_NODES * 64 + 255) / 256;   // one wave per node

    k_p1w<<<NB_X + 1 + NB1, 256, 0, stream>>>(ei, W1, x, bcnt, w1b, xb);
    k_p2<<<NBKT, 64, 0, stream>>>(bcnt, colsum);
    k_p3<<<NB1, 256, 0, stream>>>(ei, bcnt, colsum, tmp);
    k_final_gemm<<<NBKT + NB_G, 256, 0, stream>>>(tmp, colsum, row_ptr, srcs,
                                                  xb, w1b, as1, ad1,
                                                  h1b, s1, d1);
    k_agg1<<<nb_w, 256, 0, stream>>>(row_ptr, srcs, h1b, s1, d1, b1,
                                     W2, as2, ad2, h2b, s2, d2);
    k_agg2<<<nb_w, 256, 0, stream>>>(row_ptr, srcs, h2b, s2, d2, b2, out);
}

// Round 9
// 344.127 us; speedup vs baseline: 1.0296x; 1.0025x over previous
//
#include <hip/hip_runtime.h>
#include <hip/hip_bf16.h>

#define N_NODES 100000
#define N_EDGES 1600000
#define N_TOT   (N_EDGES + N_NODES)   // edges + self loops
#define F_IN    256
#define F1      64     // H1*C1
#define H1      8
#define C1      8
#define F2      32
#define SLOPE   0.2f

#define NB_G    ((N_NODES + 255) / 256)           // 391 gemm blocks
#define NB_X    3125                               // x->bf16 convert blocks (25.6e6/8192)

// counting-sort CSR build (no global atomics)
#define EB      4096                               // edges per P1/P3 block
#define NB1     ((N_EDGES + EB - 1) / EB)          // 391
#define BW      256                                // nodes per bucket
#define NBKT    ((N_NODES + BW - 1) / BW)          // 391

typedef unsigned int  uint;
typedef unsigned short ushort;
typedef __attribute__((ext_vector_type(8))) short bf16x8;
typedef __attribute__((ext_vector_type(4))) float f32x4;
typedef __attribute__((ext_vector_type(2))) float f32x2;

__device__ inline ushort f2bf(float f) {               // RNE float->bf16
    uint u = __float_as_uint(f);
    uint r = u + 0x7fffu + ((u >> 16) & 1u);
    return (ushort)(r >> 16);
}
__device__ inline float bflo(uint u) { return __uint_as_float(u << 16); }
__device__ inline float bfhi(uint u) { return __uint_as_float(u & 0xffff0000u); }
__device__ inline uint pk2bf(float a, float b) {
    __hip_bfloat162 h = __float22bfloat162_rn(make_float2(a, b));
    union { __hip_bfloat162 h; uint u; } cv; cv.h = h;
    return cv.u;
}

// Block-wide exclusive scan of colsum[NBKT] -> sb[0..NBKT] (sb[NBKT]=total).
__device__ inline void bucket_bases(const int* __restrict__ colsum,
                                    int* sc, int* sb, int tid) {
    const int i0 = 2 * tid, i1 = 2 * tid + 1;
    const int a0 = (i0 < NBKT) ? colsum[i0] : 0;
    const int a1 = (i1 < NBKT) ? colsum[i1] : 0;
    sc[tid] = a0 + a1;
    __syncthreads();
    for (int off = 1; off < 256; off <<= 1) {
        int t = (tid >= off) ? sc[tid - off] : 0;
        __syncthreads();
        sc[tid] += t;
        __syncthreads();
    }
    const int excl = sc[tid] - (a0 + a1);
    if (i0 < NBKT)  sb[i0] = excl;
    if (i1 <= NBKT) sb[i1] = excl + a0;       // writes sb[NBKT] (=total) too
    __syncthreads();
}

// ---------------------------------------------------------------------------
// Launch 1: blocks [0,NB_X) = x -> bf16 convert (streaming, BW-bound);
// block NB_X = W1 swizzled pre-convert; blocks (NB_X, NB_X+NB1] = P1
// bucket-count (LDS histogram, int2 edge loads, plain stores to bcnt).
// ---------------------------------------------------------------------------
__global__ __launch_bounds__(256) void k_p1w(
        const int* __restrict__ ei, const float* __restrict__ W1,
        const float* __restrict__ x,
        int* __restrict__ bcnt, ushort* __restrict__ w1b,
        ushort* __restrict__ xb) {
    __shared__ int H[NBKT];
    const int tid = threadIdx.x;
    if (blockIdx.x < NB_X) {                       // ---- x convert ----
        const size_t base = (size_t)blockIdx.x * 8192;
#pragma unroll
        for (int r = 0; r < 8; ++r) {
            const size_t idx = base + (size_t)r * 1024 + tid * 4;
            const float4 v = *(const float4*)(x + idx);
            *(uint2*)(xb + idx) = make_uint2(pk2bf(v.x, v.y), pk2bf(v.z, v.w));
        }
        return;
    }
    if (blockIdx.x == NB_X) {                      // ---- W1 convert ----
        for (int i = 0; i < 64; ++i) {
            const int e = i * 256 + tid;           // e = k*64 + n
            const int k = e >> 6, n = e & 63;
            w1b[((k >> 3) * 64 + n) * 8 + (k & 7)] = f2bf(W1[e]);
        }
        return;
    }
    const int blk = blockIdx.x - NB_X - 1;         // ---- P1 bucket count ----
    for (int j = tid; j < NBKT; j += 256) H[j] = 0;
    __syncthreads();
    const int e0 = blk * EB;
    const int lim = (e0 + EB < N_EDGES) ? e0 + EB : N_EDGES;
    for (int i = e0 + tid * 2; i < lim; i += 512) {    // (lim-e0) % 512 == 0
        const int2 dd = *(const int2*)&ei[N_EDGES + i];
        atomicAdd(&H[dd.x >> 8], 1);               // LDS atomic
        atomicAdd(&H[dd.y >> 8], 1);
    }
    __syncthreads();
    for (int j = tid; j < NBKT; j += 256)
        bcnt[j * NB1 + blk] = H[j];
}

// ---------------------------------------------------------------------------
// P2: per-bucket exclusive scan of bcnt[bucket][*] across blocks (in place)
// + column sums. One wave per bucket.
// ---------------------------------------------------------------------------
__global__ __launch_bounds__(64) void k_p2(
        int* __restrict__ bcnt, int* __restrict__ colsum) {
    const int col = blockIdx.x, lane = threadIdx.x;
    int carry = 0;
    for (int c0 = 0; c0 < NB1; c0 += 64) {
        const int idx = c0 + lane;
        const int v = (idx < NB1) ? bcnt[col * NB1 + idx] : 0;
        int s = v;
#pragma unroll
        for (int off = 1; off < 64; off <<= 1) {
            int u = __shfl_up(s, off);
            if (lane >= off) s += u;
        }
        if (idx < NB1) bcnt[col * NB1 + idx] = carry + s - v;
        carry += __shfl(s, 63);
    }
    if (lane == 0) colsum[col] = carry;
}

// ---------------------------------------------------------------------------
// P3: bucket scatter. int2-vectorized edge loads; places PACKED
// (dst&255)<<24 | src into bucket-ordered tmp via LDS cursors.
// ---------------------------------------------------------------------------
__global__ __launch_bounds__(256) void k_p3(
        const int* __restrict__ ei, const int* __restrict__ bcnt,
        const int* __restrict__ colsum, uint* __restrict__ tmp) {
    __shared__ int sc[256];
    __shared__ int cur[NBKT + 1];
    const int tid = threadIdx.x, blk = blockIdx.x;
    bucket_bases(colsum, sc, cur, tid);
    for (int b = tid; b < NBKT; b += 256) cur[b] += bcnt[b * NB1 + blk];
    __syncthreads();
    const int e0 = blk * EB;
    const int lim = (e0 + EB < N_EDGES) ? e0 + EB : N_EDGES;
    for (int i = e0 + tid * 2; i < lim; i += 512) {    // (lim-e0) % 512 == 0
        const int2 ss = *(const int2*)&ei[i];
        const int2 dd = *(const int2*)&ei[N_EDGES + i];
        const int p0 = atomicAdd(&cur[dd.x >> 8], 1);  // LDS atomic
        tmp[p0] = ((uint)(dd.x & 255) << 24) | (uint)ss.x;
        const int p1 = atomicAdd(&cur[dd.y >> 8], 1);
        tmp[p1] = ((uint)(dd.y & 255) << 24) | (uint)ss.y;
    }
}

// ---------------------------------------------------------------------------
// Launch 4: blocks [0,NBKT) = final CSR placement; blocks [NBKT,NBKT+NB_G)
// = MFMA gemm (h1 = xb@W1 + s1/d1 dots), A-operand loaded directly as
// bf16x8 from pre-converted xb.
// ---------------------------------------------------------------------------
__global__ __launch_bounds__(256) void k_final_gemm(
        const uint* __restrict__ tmp, const int* __restrict__ colsum,
        int* __restrict__ row_ptr, int* __restrict__ srcs,
        const ushort* __restrict__ xb, const ushort* __restrict__ w1b,
        const float* __restrict__ as1, const float* __restrict__ ad1,
        ushort* __restrict__ h1b, float* __restrict__ s1,
        float* __restrict__ d1) {
    __shared__ union {
        struct { int sc[256]; int sb[NBKT + 1]; int cur[BW]; } f;
        ushort B[F_IN * F1];        // 32 KB: W1 bf16 swizzled
        ushort S[4][64][66];        // 33.8 KB: per-wave h staging (pad 66)
    } sm;
    const int tid = threadIdx.x;

    if (blockIdx.x < NBKT) {                       // ---- final placement ----
        const int b = blockIdx.x;
        bucket_bases(colsum, sm.f.sc, sm.f.sb, tid);
        sm.f.cur[tid] = 0;
        __syncthreads();
        const int lo = sm.f.sb[b], hi = sm.f.sb[b + 1];
        for (int i = lo + tid; i < hi; i += 256)
            atomicAdd(&sm.f.cur[tmp[i] >> 24], 1);      // LDS atomic
        __syncthreads();
        const int n = b * BW + tid;
        const int myc = sm.f.cur[tid];
        const int v = (n < N_NODES) ? myc + 1 : 0;      // +1 = self loop
        __syncthreads();
        sm.f.sc[tid] = v;
        __syncthreads();
        for (int off = 1; off < 256; off <<= 1) {
            int t = (tid >= off) ? sm.f.sc[tid - off] : 0;
            __syncthreads();
            sm.f.sc[tid] += t;
            __syncthreads();
        }
        const int rp = lo + b * BW + (sm.f.sc[tid] - v);
        if (n < N_NODES) {
            row_ptr[n] = rp;
            srcs[rp] = n;                               // self loop slot 0
        }
        if (b == NBKT - 1 && tid == 255) row_ptr[N_NODES] = N_TOT;
        sm.f.cur[tid] = rp + 1;                         // edge cursor
        __syncthreads();
        for (int i = lo + tid; i < hi; i += 256) {
            const uint u = tmp[i];
            const int pos = atomicAdd(&sm.f.cur[u >> 24], 1);   // LDS atomic
            srcs[pos] = (int)(u & 0xFFFFFFu);
        }
        return;
    }

    // ---- MFMA gemm part ----
    {   // stage pre-swizzled W1: straight 32 KB vector copy
        const uint4* s4 = (const uint4*)w1b;
        uint4* d4 = (uint4*)sm.B;
#pragma unroll
        for (int i = 0; i < 8; ++i)
            d4[i * 256 + tid] = s4[i * 256 + tid];
    }
    __syncthreads();

    const int wave = tid >> 6, lane = tid & 63;
    const int q = lane >> 4, ln = lane & 15;
    const int rowbase = (blockIdx.x - NBKT) * 256 + wave * 64;

    f32x4 acc[4][4];
#pragma unroll
    for (int mt = 0; mt < 4; ++mt)
#pragma unroll
        for (int nt = 0; nt < 4; ++nt) acc[mt][nt] = (f32x4){0.f, 0.f, 0.f, 0.f};

    const ushort* xrow[4];
#pragma unroll
    for (int mt = 0; mt < 4; ++mt) {
        const int r = rowbase + mt * 16 + ln;
        const int rc = r < N_NODES ? r : N_NODES - 1;
        xrow[mt] = xb + (size_t)rc * F_IN + q * 8;
    }

#pragma unroll 4
    for (int t = 0; t < 8; ++t) {                  // K-loop: 8 x 32
        bf16x8 bfr[4];
#pragma unroll
        for (int nt = 0; nt < 4; ++nt)
            bfr[nt] = *(const bf16x8*)&sm.B[((t * 4 + q) * 64 + nt * 16 + ln) * 8];
        bf16x8 af[4];
#pragma unroll
        for (int mt = 0; mt < 4; ++mt)
            af[mt] = *(const bf16x8*)(xrow[mt] + t * 32);
#pragma unroll
        for (int mt = 0; mt < 4; ++mt)
#pragma unroll
            for (int nt = 0; nt < 4; ++nt)
                acc[mt][nt] = __builtin_amdgcn_mfma_f32_16x16x32_bf16(
                                  af[mt], bfr[nt], acc[mt][nt], 0, 0, 0);
    }
    __syncthreads();

    // stage h (bf16): C/D layout col=lane&15, row=q*4+r
#pragma unroll
    for (int mt = 0; mt < 4; ++mt)
#pragma unroll
        for (int nt = 0; nt < 4; ++nt)
#pragma unroll
            for (int r = 0; r < 4; ++r)
                sm.S[wave][mt * 16 + q * 4 + r][nt * 16 + ln] = f2bf(acc[mt][nt][r]);
    __syncthreads();

    const int node = rowbase + lane;
    if (node >= N_NODES) return;
    const uint* srow = (const uint*)&sm.S[wave][lane][0];
    float sacc[H1], dacc[H1];
#pragma unroll
    for (int h = 0; h < H1; ++h) { sacc[h] = 0.f; dacc[h] = 0.f; }
    uint4* hout = (uint4*)(h1b + (size_t)node * F1);
#pragma unroll
    for (int p4 = 0; p4 < 8; ++p4) {               // p4 == head index
        const uint u0 = srow[p4 * 4 + 0], u1 = srow[p4 * 4 + 1];
        const uint u2 = srow[p4 * 4 + 2], u3 = srow[p4 * 4 + 3];
        hout[p4] = make_uint4(u0, u1, u2, u3);
        const float c[8] = {bflo(u0), bfhi(u0), bflo(u1), bfhi(u1),
                            bflo(u2), bfhi(u2), bflo(u3), bfhi(u3)};
#pragma unroll
        for (int j = 0; j < 8; ++j) {
            sacc[p4] += c[j] * as1[p4 * 8 + j];
            dacc[p4] += c[j] * ad1[p4 * 8 + j];
        }
    }
    float4* s4 = (float4*)(s1 + (size_t)node * H1);
    float4* d4 = (float4*)(d1 + (size_t)node * H1);
    s4[0] = make_float4(sacc[0], sacc[1], sacc[2], sacc[3]);
    s4[1] = make_float4(sacc[4], sacc[5], sacc[6], sacc[7]);
    d4[0] = make_float4(dacc[0], dacc[1], dacc[2], dacc[3]);
    d4[1] = make_float4(dacc[4], dacc[5], dacc[6], dacc[7]);
}

// ---------------------------------------------------------------------------
// K_agg1 (+ fused node GEMM): 4 lanes/edge (16 groups) -> a deg-17 node
// issues all gathers in ONE round (16 edges in flight/wave vs 8). Lane owns
// a head PAIR (heads 2*(lane&3), +1): float2 s-load, 2 exps (still 1 per
// (edge,head)), 2x uint4 h-loads, f32x2 accum, f32x2 per-head z. Reduce-
// scatter over bits 2..5 (head-select at off=4, z scattered there) leaves
// each lane ONE x2 channel; all-lane elu; fused 64x32 W2 GEMM + s2/d2 dots.
// ---------------------------------------------------------------------------
__global__ __launch_bounds__(256) void k_agg1(
        const int* __restrict__ row_ptr, const int* __restrict__ srcs,
        const ushort* __restrict__ h1b, const float* __restrict__ s1,
        const float* __restrict__ d1, const float* __restrict__ b1,
        const float* __restrict__ W2, const float* __restrict__ as2,
        const float* __restrict__ ad2,
        ushort* __restrict__ h2b, float* __restrict__ s2,
        float* __restrict__ d2) {
    __shared__ float sx[4][64];                    // per-wave x2 row (f32)
    const int wid = (blockIdx.x * 256 + threadIdx.x) >> 6;
    if (wid >= N_NODES) return;
    const int w = threadIdx.x >> 6;
    const int lane = threadIdx.x & 63;
    const int q = lane >> 2;          // edge group 0..15
    const int cp = lane & 3;          // head pair: heads 2cp, 2cp+1
    const float2 dh2 = *(const float2*)((const char*)d1 + (size_t)wid * 32 + 8 * cp);
    const int beg = row_ptr[wid], end = row_ptr[wid + 1];
    const char* hP = (const char*)h1b;        // 128B rows, 12.8 MB
    const char* sP = (const char*)s1;         // 32B rows, 3.2 MB
    const uint hOff = 32u * (uint)cp;
    const uint sOff = 8u * (uint)cp;
    f32x2 A0 = {0.f, 0.f}, A1 = {0.f, 0.f}, A2 = {0.f, 0.f}, A3 = {0.f, 0.f};
    f32x2 A4 = {0.f, 0.f}, A5 = {0.f, 0.f}, A6 = {0.f, 0.f}, A7 = {0.f, 0.f};
    f32x2 z2 = {0.f, 0.f};
    for (int i = beg + q; i < end; i += 16) {
        const int nA = srcs[i];
        const float2 sv2 = *(const float2*)(sP + ((uint)nA * 32u + sOff));
        float e0 = sv2.x + dh2.x, e1 = sv2.y + dh2.y;
        e0 = fmaxf(e0, SLOPE * e0);            // leaky (slope<1)
        e1 = fmaxf(e1, SLOPE * e1);
        const float x0 = __expf(e0), x1 = __expf(e1);
        const uint base = (uint)nA * 128u + hOff;
        const uint4 U0 = *(const uint4*)(hP + base);
        const uint4 U1 = *(const uint4*)(hP + base + 16);
        z2 += (f32x2){x0, x1};
        const f32x2 xa0 = {x0, x0}, xa1 = {x1, x1};
        A0 += xa0 * (f32x2){bflo(U0.x), bfhi(U0.x)};
        A1 += xa0 * (f32x2){bflo(U0.y), bfhi(U0.y)};
        A2 += xa0 * (f32x2){bflo(U0.z), bfhi(U0.z)};
        A3 += xa0 * (f32x2){bflo(U0.w), bfhi(U0.w)};
        A4 += xa1 * (f32x2){bflo(U1.x), bfhi(U1.x)};
        A5 += xa1 * (f32x2){bflo(U1.y), bfhi(U1.y)};
        A6 += xa1 * (f32x2){bflo(U1.z), bfhi(U1.z)};
        A7 += xa1 * (f32x2){bflo(U1.w), bfhi(U1.w)};
    }
    // ---- reduce-scatter over bits 2..5: lane ends with one channel ----
    f32x2 r0, r1, r2, r3;
    float zf;
    {   // off=4 (bit2 = head within pair, +8 ch); z scattered here too
        const bool hi = lane & 4;
        f32x2 s0 = hi ? A0 : A4, s1v = hi ? A1 : A5;
        f32x2 s2v = hi ? A2 : A6, s3v = hi ? A3 : A7;
        const f32x2 k0 = hi ? A4 : A0, k1 = hi ? A5 : A1;
        const f32x2 k2 = hi ? A6 : A2, k3 = hi ? A7 : A3;
        s0.x = __shfl_xor(s0.x, 4); s0.y = __shfl_xor(s0.y, 4);
        s1v.x = __shfl_xor(s1v.x, 4); s1v.y = __shfl_xor(s1v.y, 4);
        s2v.x = __shfl_xor(s2v.x, 4); s2v.y = __shfl_xor(s2v.y, 4);
        s3v.x = __shfl_xor(s3v.x, 4); s3v.y = __shfl_xor(s3v.y, 4);
        r0 = k0 + s0; r1 = k1 + s1v; r2 = k2 + s2v; r3 = k3 + s3v;
        float zs = hi ? z2.x : z2.y;
        const float zk = hi ? z2.y : z2.x;
        zs = __shfl_xor(zs, 4);
        zf = zk + zs;
    }
    {   // off=8 (bit3, +4 ch)
        const bool hi = lane & 8;
        f32x2 s0 = hi ? r0 : r2, s1v = hi ? r1 : r3;
        const f32x2 k0 = hi ? r2 : r0, k1 = hi ? r3 : r1;
        s0.x = __shfl_xor(s0.x, 8); s0.y = __shfl_xor(s0.y, 8);
        s1v.x = __shfl_xor(s1v.x, 8); s1v.y = __shfl_xor(s1v.y, 8);
        r0 = k0 + s0; r1 = k1 + s1v;
    }
    {   // off=16 (bit4, +2 ch)
        const bool hi = lane & 16;
        f32x2 s0 = hi ? r0 : r1;
        const f32x2 k0 = hi ? r1 : r0;
        s0.x = __shfl_xor(s0.x, 16); s0.y = __shfl_xor(s0.y, 16);
        r0 = k0 + s0;
    }
    float sv;
    {   // off=32 (bit5, +1 ch)
        const bool hi = lane & 32;
        float s0 = hi ? r0.x : r0.y;
        const float k0 = hi ? r0.y : r0.x;
        s0 = __shfl_xor(s0, 32);
        sv = k0 + s0;
    }
    zf += __shfl_xor(zf, 8); zf += __shfl_xor(zf, 16); zf += __shfl_xor(zf, 32);

    const int xi = cp * 16 + ((lane >> 2) & 1) * 8 + ((lane >> 3) & 1) * 4
                 + ((lane >> 4) & 1) * 2 + ((lane >> 5) & 1);
    const float zi = 1.f / (zf + 1e-16f);
    float xv = sv * zi + b1[xi];
    xv = xv > 0.f ? xv : __expf(xv) - 1.f;     // elu, all 64 lanes (1 each)
    sx[w][xi] = xv;                            // permutation: conflict-free
    __builtin_amdgcn_wave_barrier();           // in-wave LDS RAW ordering

    // fused node GEMM: h2[oc] = sum_k x2[k] * W2[k][oc]  (lane: kh half, oc)
    const int kh = lane >> 5;          // K half 0..1
    const int oc = lane & 31;          // output channel
    const float4* sxv = (const float4*)&sx[w][kh * 32];   // broadcast reads
    const float* wp0 = W2 + (size_t)(kh * 32) * F2 + oc;  // coalesced 128B/half
    float acc = 0.f;
#pragma unroll
    for (int k4 = 0; k4 < 8; ++k4) {
        const float4 xv4 = sxv[k4];
        const float* wp = wp0 + (size_t)k4 * 4 * F2;
        acc += xv4.x * wp[0]      + xv4.y * wp[F2]
             + xv4.z * wp[2 * F2] + xv4.w * wp[3 * F2];
    }
    acc += __shfl_xor(acc, 32);        // combine K halves; all lanes have h2[oc]

    float sA2 = acc * as2[oc], dA2 = acc * ad2[oc];
#pragma unroll
    for (int off = 1; off <= 16; off <<= 1) {
        sA2 += __shfl_xor(sA2, off);
        dA2 += __shfl_xor(dA2, off);
    }
    const float accp = __shfl_xor(acc, 1);     // partner channel (oc^1)
    if (lane < 32 && !(lane & 1))
        *(uint*)&h2b[(size_t)wid * F2 + oc] = pk2bf(acc, accp);
    if (lane == 0) { s2[wid] = sA2; d2[wid] = dA2; }
}

// ---------------------------------------------------------------------------
// K_agg2: 2 lanes/edge (32 groups; lane bit0 = channel half, 2x uint4 per
// lane). Reduce-scatter over bits 1-4 (+ combine over bit 5) leaves each
// lane one class logit; 1 exp/lane softmax tail. Writes d_out.
// ---------------------------------------------------------------------------
__global__ __launch_bounds__(256) void k_agg2(
        const int* __restrict__ row_ptr, const int* __restrict__ srcs,
        const ushort* __restrict__ h2b, const float* __restrict__ s2,
        const float* __restrict__ d2, const float* __restrict__ b2,
        float* __restrict__ out) {
    const int wid = (blockIdx.x * 256 + threadIdx.x) >> 6;
    if (wid >= N_NODES) return;
    const int lane = threadIdx.x & 63;
    const int q = lane >> 1;          // edge group 0..31
    const int ch = lane & 1;          // channel half: channels 16ch..16ch+15
    const float dn = d2[wid];
    const int beg = row_ptr[wid], end = row_ptr[wid + 1];
    const char* hP = (const char*)h2b;        // 64B rows, 6.4 MB
    const char* sP = (const char*)s2;         // 4B, 0.4 MB
    const uint ch32 = 32u * (uint)ch;
    f32x2 A0 = {0.f, 0.f}, A1 = {0.f, 0.f}, A2 = {0.f, 0.f}, A3 = {0.f, 0.f};
    f32x2 A4 = {0.f, 0.f}, A5 = {0.f, 0.f}, A6 = {0.f, 0.f}, A7 = {0.f, 0.f};
    float z = 0.f;
    for (int i = beg + q; i < end; i += 32) {
        const int nA = srcs[i];
        float eA = *(const float*)(sP + (uint)nA * 4u) + dn;
        eA = fmaxf(eA, SLOPE * eA);
        const float xA = __expf(eA);
        const uint off = (uint)nA * 64u + ch32;
        const uint4 U0 = *(const uint4*)(hP + off);
        const uint4 U1 = *(const uint4*)(hP + off + 16);
        z += xA;
        const f32x2 xa = {xA, xA};
        A0 += xa * (f32x2){bflo(U0.x), bfhi(U0.x)};
        A1 += xa * (f32x2){bflo(U0.y), bfhi(U0.y)};
        A2 += xa * (f32x2){bflo(U0.z), bfhi(U0.z)};
        A3 += xa * (f32x2){bflo(U0.w), bfhi(U0.w)};
        A4 += xa * (f32x2){bflo(U1.x), bfhi(U1.x)};
        A5 += xa * (f32x2){bflo(U1.y), bfhi(U1.y)};
        A6 += xa * (f32x2){bflo(U1.z), bfhi(U1.z)};
        A7 += xa * (f32x2){bflo(U1.w), bfhi(U1.w)};
    }
    // ---- reduce-scatter over bits 1,2,3,4; plain combine over bit 5 ----
    f32x2 r0, r1, r2, r3;
    {   // off=2 (bit1 -> rel-ch +8): 8 -> 4
        const bool hi = lane & 2;
        f32x2 s0 = hi ? A0 : A4, s1v = hi ? A1 : A5;
        f32x2 s2v = hi ? A2 : A6, s3v = hi ? A3 : A7;
        const f32x2 k0 = hi ? A4 : A0, k1 = hi ? A5 : A1;
        const f32x2 k2 = hi ? A6 : A2, k3 = hi ? A7 : A3;
        s0.x = __shfl_xor(s0.x, 2); s0.y = __shfl_xor(s0.y, 2);
        s1v.x = __shfl_xor(s1v.x, 2); s1v.y = __shfl_xor(s1v.y, 2);
        s2v.x = __shfl_xor(s2v.x, 2); s2v.y = __shfl_xor(s2v.y, 2);
        s3v.x = __shfl_xor(s3v.x, 2); s3v.y = __shfl_xor(s3v.y, 2);
        r0 = k0 + s0; r1 = k1 + s1v; r2 = k2 + s2v; r3 = k3 + s3v;
    }
    {   // off=4 (bit2 -> rel-ch +4): 4 -> 2
        const bool hi = lane & 4;
        f32x2 s0 = hi ? r0 : r2, s1v = hi ? r1 : r3;
        const f32x2 k0 = hi ? r2 : r0, k1 = hi ? r3 : r1;
        s0.x = __shfl_xor(s0.x, 4); s0.y = __shfl_xor(s0.y, 4);
        s1v.x = __shfl_xor(s1v.x, 4); s1v.y = __shfl_xor(s1v.y, 4);
        r0 = k0 + s0; r1 = k1 + s1v;
    }
    {   // off=8 (bit3 -> rel-ch +2): 2 -> 1
        const bool hi = lane & 8;
        f32x2 s0 = hi ? r0 : r1;
        const f32x2 k0 = hi ? r1 : r0;
        s0.x = __shfl_xor(s0.x, 8); s0.y = __shfl_xor(s0.y, 8);
        r0 = k0 + s0;
    }
    float sv;
    {   // off=16 (bit4 -> rel-ch +1): f32x2 -> float
        const bool hi = lane & 16;
        float s0 = hi ? r0.x : r0.y;
        const float k0 = hi ? r0.y : r0.x;
        s0 = __shfl_xor(s0, 16);
        sv = k0 + s0;
    }
    sv += __shfl_xor(sv, 32);          // lanes l, l^32 now duplicate
    z += __shfl_xor(z, 2); z += __shfl_xor(z, 4); z += __shfl_xor(z, 8);
    z += __shfl_xor(z, 16); z += __shfl_xor(z, 32);

    const int elem = ch * 16 + ((lane >> 1) & 1) * 8 + ((lane >> 2) & 1) * 4
                   + ((lane >> 3) & 1) * 2 + ((lane >> 4) & 1);
    const float zi = 1.f / (z + 1e-16f);
    const float v = sv * zi + b2[elem];
    // log-softmax over the 32 classes: each 32-lane half holds all 32 once.
    float m = v;
#pragma unroll
    for (int off = 1; off <= 16; off <<= 1) m = fmaxf(m, __shfl_xor(m, off));
    float ssum = __expf(v - m);
#pragma unroll
    for (int off = 1; off <= 16; off <<= 1) ssum += __shfl_xor(ssum, off);
    const float lse = m + __logf(ssum);
    if (lane < 32) out[(size_t)wid * F2 + elem] = v - lse;
}

extern "C" void kernel_launch(void* const* d_in, const int* in_sizes, int n_in,
                              void* d_out, int out_size, void* d_ws, size_t ws_size,
                              hipStream_t stream) {
    const float* x   = (const float*)d_in[0];
    const int*   ei  = (const int*)d_in[1];
    const float* W1  = (const float*)d_in[2];
    const float* as1 = (const float*)d_in[3];
    const float* ad1 = (const float*)d_in[4];
    const float* b1  = (const float*)d_in[5];
    const float* W2  = (const float*)d_in[6];
    const float* as2 = (const float*)d_in[7];
    const float* ad2 = (const float*)d_in[8];
    const float* b2  = (const float*)d_in[9];
    float* out = (float*)d_out;

    // Workspace layout
    ushort* xb  = (ushort*)d_ws;                   // N*256 bf16 (51.2 MB)
    ushort* h1b = xb + (size_t)N_NODES * F_IN;     // N*64 bf16 (128B rows)
    ushort* h2b = h1b + (size_t)N_NODES * F1;      // N*32 bf16
    ushort* w1b = h2b + (size_t)N_NODES * F2;      // 16384 bf16 (swizzled W1)
    float*  s1  = (float*)(w1b + F_IN * F1);       // N*8
    float*  d1  = s1 + (size_t)N_NODES * H1;       // N*8
    float*  s2  = d1 + (size_t)N_NODES * H1;       // N
    float*  d2  = s2 + N_NODES;                    // N
    uint*   tmp = (uint*)(d2 + N_NODES);           // N_EDGES (packed)
    int* row_ptr = (int*)(tmp + N_EDGES);          // N+1
    int* colsum  = row_ptr + N_NODES + 1;          // NBKT
    int* bcnt    = colsum + NBKT;                  // NBKT*NB1
    int* srcs    = bcnt + (size_t)NBKT * NB1;      // N_TOT

    const int nb_w = (N_NODES * 64 + 255) / 256;   // one wave per node

    k_p1w<<<NB_X + 1 + NB1, 256, 0, stream>>>(ei, W1, x, bcnt, w1b, xb);
    k_p2<<<NBKT, 64, 0, stream>>>(bcnt, colsum);
    k_p3<<<NB1, 256, 0, stream>>>(ei, bcnt, colsum, tmp);
    k_final_gemm<<<NBKT + NB_G, 256, 0, stream>>>(tmp, colsum, row_ptr, srcs,
                                                  xb, w1b, as1, ad1,
                                                  h1b, s1, d1);
    k_agg1<<<nb_w, 256, 0, stream>>>(row_ptr, srcs, h1b, s1, d1, b1,
                                     W2, as2, ad2, h2b, s2, d2);
    k_agg2<<<nb_w, 256, 0, stream>>>(row_ptr, srcs, h2b, s2, d2, b2, out);
}

// Round 10
// 333.845 us; speedup vs baseline: 1.0614x; 1.0308x over previous
//
#include <hip/hip_runtime.h>
#include <hip/hip_bf16.h>

#define N_NODES 100000
#define N_EDGES 1600000
#define N_TOT   (N_EDGES + N_NODES)   // edges + self loops
#define F_IN    256
#define F1      64     // H1*C1
#define H1      8
#define C1      8
#define F2      32
#define SLOPE   0.2f

#define NB_G2   ((N_NODES + 63) / 64)             // 1563 gemm blocks (64 rows each)

// counting-sort CSR build (no global atomics)
#define EB      4096                               // edges per P1/P3 block
#define NB1     ((N_EDGES + EB - 1) / EB)          // 391
#define BW      256                                // nodes per bucket
#define NBKT    ((N_NODES + BW - 1) / BW)          // 391

typedef unsigned int  uint;
typedef unsigned short ushort;
typedef __attribute__((ext_vector_type(8))) short bf16x8;
typedef __attribute__((ext_vector_type(4))) float f32x4;
typedef __attribute__((ext_vector_type(2))) float f32x2;

__device__ inline ushort f2bf(float f) {               // RNE float->bf16
    uint u = __float_as_uint(f);
    uint r = u + 0x7fffu + ((u >> 16) & 1u);
    return (ushort)(r >> 16);
}
__device__ inline float bflo(uint u) { return __uint_as_float(u << 16); }
__device__ inline float bfhi(uint u) { return __uint_as_float(u & 0xffff0000u); }
__device__ inline uint pk2bf(float a, float b) {
    __hip_bfloat162 h = __float22bfloat162_rn(make_float2(a, b));
    union { __hip_bfloat162 h; uint u; } cv; cv.h = h;
    return cv.u;
}

// Block-wide exclusive scan of colsum[NBKT] -> sb[0..NBKT] (sb[NBKT]=total).
__device__ inline void bucket_bases(const int* __restrict__ colsum,
                                    int* sc, int* sb, int tid) {
    const int i0 = 2 * tid, i1 = 2 * tid + 1;
    const int a0 = (i0 < NBKT) ? colsum[i0] : 0;
    const int a1 = (i1 < NBKT) ? colsum[i1] : 0;
    sc[tid] = a0 + a1;
    __syncthreads();
    for (int off = 1; off < 256; off <<= 1) {
        int t = (tid >= off) ? sc[tid - off] : 0;
        __syncthreads();
        sc[tid] += t;
        __syncthreads();
    }
    const int excl = sc[tid] - (a0 + a1);
    if (i0 < NBKT)  sb[i0] = excl;
    if (i1 <= NBKT) sb[i1] = excl + a0;       // writes sb[NBKT] (=total) too
    __syncthreads();
}

// ---------------------------------------------------------------------------
// Launch 1: blocks [0,NB1) = P1 bucket-count (LDS histogram, int2 edge
// loads, plain stores to bcnt); block NB1 = W1 swizzled bf16 pre-convert
// (read from GLOBAL by every gemm block -- L2-broadcast, no LDS staging).
// ---------------------------------------------------------------------------
__global__ __launch_bounds__(256) void k_p1w(
        const int* __restrict__ ei, const float* __restrict__ W1,
        int* __restrict__ bcnt, ushort* __restrict__ w1b) {
    __shared__ int H[NBKT];
    const int tid = threadIdx.x;
    if (blockIdx.x == NB1) {                       // ---- W1 convert ----
        for (int i = 0; i < 64; ++i) {
            const int e = i * 256 + tid;           // e = k*64 + n
            const int k = e >> 6, n = e & 63;
            w1b[((k >> 3) * 64 + n) * 8 + (k & 7)] = f2bf(W1[e]);
        }
        return;
    }
    const int blk = blockIdx.x;                    // ---- P1 bucket count ----
    for (int j = tid; j < NBKT; j += 256) H[j] = 0;
    __syncthreads();
    const int e0 = blk * EB;
    const int lim = (e0 + EB < N_EDGES) ? e0 + EB : N_EDGES;
    for (int i = e0 + tid * 2; i < lim; i += 512) {    // (lim-e0) % 512 == 0
        const int2 dd = *(const int2*)&ei[N_EDGES + i];
        atomicAdd(&H[dd.x >> 8], 1);               // LDS atomic
        atomicAdd(&H[dd.y >> 8], 1);
    }
    __syncthreads();
    for (int j = tid; j < NBKT; j += 256)
        bcnt[j * NB1 + blk] = H[j];
}

// ---------------------------------------------------------------------------
// P2: per-bucket exclusive scan of bcnt[bucket][*] across blocks (in place)
// + column sums. One wave per bucket.
// ---------------------------------------------------------------------------
__global__ __launch_bounds__(64) void k_p2(
        int* __restrict__ bcnt, int* __restrict__ colsum) {
    const int col = blockIdx.x, lane = threadIdx.x;
    int carry = 0;
    for (int c0 = 0; c0 < NB1; c0 += 64) {
        const int idx = c0 + lane;
        const int v = (idx < NB1) ? bcnt[col * NB1 + idx] : 0;
        int s = v;
#pragma unroll
        for (int off = 1; off < 64; off <<= 1) {
            int u = __shfl_up(s, off);
            if (lane >= off) s += u;
        }
        if (idx < NB1) bcnt[col * NB1 + idx] = carry + s - v;
        carry += __shfl(s, 63);
    }
    if (lane == 0) colsum[col] = carry;
}

// ---------------------------------------------------------------------------
// P3: bucket scatter. int2-vectorized edge loads; places PACKED
// (dst&255)<<24 | src into bucket-ordered tmp via LDS cursors.
// ---------------------------------------------------------------------------
__global__ __launch_bounds__(256) void k_p3(
        const int* __restrict__ ei, const int* __restrict__ bcnt,
        const int* __restrict__ colsum, uint* __restrict__ tmp) {
    __shared__ int sc[256];
    __shared__ int cur[NBKT + 1];
    const int tid = threadIdx.x, blk = blockIdx.x;
    bucket_bases(colsum, sc, cur, tid);
    for (int b = tid; b < NBKT; b += 256) cur[b] += bcnt[b * NB1 + blk];
    __syncthreads();
    const int e0 = blk * EB;
    const int lim = (e0 + EB < N_EDGES) ? e0 + EB : N_EDGES;
    for (int i = e0 + tid * 2; i < lim; i += 512) {    // (lim-e0) % 512 == 0
        const int2 ss = *(const int2*)&ei[i];
        const int2 dd = *(const int2*)&ei[N_EDGES + i];
        const int p0 = atomicAdd(&cur[dd.x >> 8], 1);  // LDS atomic
        tmp[p0] = ((uint)(dd.x & 255) << 24) | (uint)ss.x;
        const int p1 = atomicAdd(&cur[dd.y >> 8], 1);
        tmp[p1] = ((uint)(dd.y & 255) << 24) | (uint)ss.y;
    }
}

// ---------------------------------------------------------------------------
// Launch 4: blocks [0,NBKT) = final CSR placement; blocks [NBKT,NBKT+NB_G2)
// = MFMA gemm, 64 rows/block (4 waves x 16 rows). Occupancy fix for the
// old 391-block gemm (R6: 18.6% occ, VALUBusy 3.6% -- naked load latency
// at 1.5 blocks/CU): 4x more blocks, B-frags read DIRECTLY from global
// w1b (32KB, L2-broadcast; no LDS staging, no 4-way bank conflicts, LDS
// drops 33.8KB -> 8.5KB), A read as f32 + inline pk2bf (no xb pass: saves
// a 150MB convert stream).
// ---------------------------------------------------------------------------
__global__ __launch_bounds__(256) void k_final_gemm(
        const uint* __restrict__ tmp, const int* __restrict__ colsum,
        int* __restrict__ row_ptr, int* __restrict__ srcs,
        const float* __restrict__ x, const ushort* __restrict__ w1b,
        const float* __restrict__ as1, const float* __restrict__ ad1,
        ushort* __restrict__ h1b, float* __restrict__ s1,
        float* __restrict__ d1) {
    __shared__ union {
        struct { int sc[256]; int sb[NBKT + 1]; int cur[BW]; } f;
        ushort S[4][16][66];        // 8.4 KB per-wave h staging (pad 66)
    } sm;
    const int tid = threadIdx.x;

    if (blockIdx.x < NBKT) {                       // ---- final placement ----
        const int b = blockIdx.x;
        bucket_bases(colsum, sm.f.sc, sm.f.sb, tid);
        sm.f.cur[tid] = 0;
        __syncthreads();
        const int lo = sm.f.sb[b], hi = sm.f.sb[b + 1];
        for (int i = lo + tid; i < hi; i += 256)
            atomicAdd(&sm.f.cur[tmp[i] >> 24], 1);      // LDS atomic
        __syncthreads();
        const int n = b * BW + tid;
        const int myc = sm.f.cur[tid];
        const int v = (n < N_NODES) ? myc + 1 : 0;      // +1 = self loop
        __syncthreads();
        sm.f.sc[tid] = v;
        __syncthreads();
        for (int off = 1; off < 256; off <<= 1) {
            int t = (tid >= off) ? sm.f.sc[tid - off] : 0;
            __syncthreads();
            sm.f.sc[tid] += t;
            __syncthreads();
        }
        const int rp = lo + b * BW + (sm.f.sc[tid] - v);
        if (n < N_NODES) {
            row_ptr[n] = rp;
            srcs[rp] = n;                               // self loop slot 0
        }
        if (b == NBKT - 1 && tid == 255) row_ptr[N_NODES] = N_TOT;
        sm.f.cur[tid] = rp + 1;                         // edge cursor
        __syncthreads();
        for (int i = lo + tid; i < hi; i += 256) {
            const uint u = tmp[i];
            const int pos = atomicAdd(&sm.f.cur[u >> 24], 1);   // LDS atomic
            srcs[pos] = (int)(u & 0xFFFFFFu);
        }
        return;
    }

    // ---- MFMA gemm part: 64 rows, 4 waves x 16 rows ----
    const int wave = tid >> 6, lane = tid & 63;
    const int q = lane >> 4, ln = lane & 15;
    const int rowbase = (blockIdx.x - NBKT) * 64 + wave * 16;
    const int row = rowbase + ln;
    const int rowc = row < N_NODES ? row : N_NODES - 1;
    const float* xr = x + (size_t)rowc * F_IN + q * 8;

    f32x4 acc[4];
#pragma unroll
    for (int nt = 0; nt < 4; ++nt) acc[nt] = (f32x4){0.f, 0.f, 0.f, 0.f};

#pragma unroll 4
    for (int t = 0; t < 8; ++t) {                  // K-loop: 8 x 32
        const float4 a0 = *(const float4*)(xr + t * 32);
        const float4 a1 = *(const float4*)(xr + t * 32 + 4);
        uint4 au = make_uint4(pk2bf(a0.x, a0.y), pk2bf(a0.z, a0.w),
                              pk2bf(a1.x, a1.y), pk2bf(a1.z, a1.w));
        bf16x8 af = *(bf16x8*)&au;
        bf16x8 bfr[4];
#pragma unroll
        for (int nt = 0; nt < 4; ++nt)
            bfr[nt] = *(const bf16x8*)&w1b[((t * 4 + q) * 64 + nt * 16 + ln) * 8];
#pragma unroll
        for (int nt = 0; nt < 4; ++nt)
            acc[nt] = __builtin_amdgcn_mfma_f32_16x16x32_bf16(
                          af, bfr[nt], acc[nt], 0, 0, 0);
    }

    // stage h (bf16): C/D layout col=lane&15 (channel), row=q*4+r (node)
#pragma unroll
    for (int nt = 0; nt < 4; ++nt)
#pragma unroll
        for (int r = 0; r < 4; ++r)
            sm.S[wave][q * 4 + r][nt * 16 + ln] = f2bf(acc[nt][r]);
    __builtin_amdgcn_wave_barrier();               // per-wave staging

    if (lane >= 16) return;
    const int node = rowbase + lane;
    if (node >= N_NODES) return;
    const uint* srow = (const uint*)&sm.S[wave][lane][0];
    float sacc[H1], dacc[H1];
#pragma unroll
    for (int h = 0; h < H1; ++h) { sacc[h] = 0.f; dacc[h] = 0.f; }
    uint4* hout = (uint4*)(h1b + (size_t)node * F1);
#pragma unroll
    for (int p4 = 0; p4 < 8; ++p4) {               // p4 == head index
        const uint u0 = srow[p4 * 4 + 0], u1 = srow[p4 * 4 + 1];
        const uint u2 = srow[p4 * 4 + 2], u3 = srow[p4 * 4 + 3];
        hout[p4] = make_uint4(u0, u1, u2, u3);
        const float c[8] = {bflo(u0), bfhi(u0), bflo(u1), bfhi(u1),
                            bflo(u2), bfhi(u2), bflo(u3), bfhi(u3)};
#pragma unroll
        for (int j = 0; j < 8; ++j) {
            sacc[p4] += c[j] * as1[p4 * 8 + j];
            dacc[p4] += c[j] * ad1[p4 * 8 + j];
        }
    }
    float4* s4 = (float4*)(s1 + (size_t)node * H1);
    float4* d4 = (float4*)(d1 + (size_t)node * H1);
    s4[0] = make_float4(sacc[0], sacc[1], sacc[2], sacc[3]);
    s4[1] = make_float4(sacc[4], sacc[5], sacc[6], sacc[7]);
    d4[0] = make_float4(dacc[0], dacc[1], dacc[2], dacc[3]);
    d4[1] = make_float4(dacc[4], dacc[5], dacc[6], dacc[7]);
}

// ---------------------------------------------------------------------------
// K_agg1 (+ fused node GEMM): 4 lanes/edge (16 groups); lane owns a head
// PAIR. Structural floor confirmed (R8/R9): bound by random 128B gathers,
// 69% forced L2 miss (12.8MB table vs 4MB/XCD L2) at ~2.3 TB/s fabric.
// ---------------------------------------------------------------------------
__global__ __launch_bounds__(256) void k_agg1(
        const int* __restrict__ row_ptr, const int* __restrict__ srcs,
        const ushort* __restrict__ h1b, const float* __restrict__ s1,
        const float* __restrict__ d1, const float* __restrict__ b1,
        const float* __restrict__ W2, const float* __restrict__ as2,
        const float* __restrict__ ad2,
        ushort* __restrict__ h2b, float* __restrict__ s2,
        float* __restrict__ d2) {
    __shared__ float sx[4][64];                    // per-wave x2 row (f32)
    const int wid = (blockIdx.x * 256 + threadIdx.x) >> 6;
    if (wid >= N_NODES) return;
    const int w = threadIdx.x >> 6;
    const int lane = threadIdx.x & 63;
    const int q = lane >> 2;          // edge group 0..15
    const int cp = lane & 3;          // head pair: heads 2cp, 2cp+1
    const float2 dh2 = *(const float2*)((const char*)d1 + (size_t)wid * 32 + 8 * cp);
    const int beg = row_ptr[wid], end = row_ptr[wid + 1];
    const char* hP = (const char*)h1b;        // 128B rows, 12.8 MB
    const char* sP = (const char*)s1;         // 32B rows, 3.2 MB
    const uint hOff = 32u * (uint)cp;
    const uint sOff = 8u * (uint)cp;
    f32x2 A0 = {0.f, 0.f}, A1 = {0.f, 0.f}, A2 = {0.f, 0.f}, A3 = {0.f, 0.f};
    f32x2 A4 = {0.f, 0.f}, A5 = {0.f, 0.f}, A6 = {0.f, 0.f}, A7 = {0.f, 0.f};
    f32x2 z2 = {0.f, 0.f};
    for (int i = beg + q; i < end; i += 16) {
        const int nA = srcs[i];
        const float2 sv2 = *(const float2*)(sP + ((uint)nA * 32u + sOff));
        float e0 = sv2.x + dh2.x, e1 = sv2.y + dh2.y;
        e0 = fmaxf(e0, SLOPE * e0);            // leaky (slope<1)
        e1 = fmaxf(e1, SLOPE * e1);
        const float x0 = __expf(e0), x1 = __expf(e1);
        const uint base = (uint)nA * 128u + hOff;
        const uint4 U0 = *(const uint4*)(hP + base);
        const uint4 U1 = *(const uint4*)(hP + base + 16);
        z2 += (f32x2){x0, x1};
        const f32x2 xa0 = {x0, x0}, xa1 = {x1, x1};
        A0 += xa0 * (f32x2){bflo(U0.x), bfhi(U0.x)};
        A1 += xa0 * (f32x2){bflo(U0.y), bfhi(U0.y)};
        A2 += xa0 * (f32x2){bflo(U0.z), bfhi(U0.z)};
        A3 += xa0 * (f32x2){bflo(U0.w), bfhi(U0.w)};
        A4 += xa1 * (f32x2){bflo(U1.x), bfhi(U1.x)};
        A5 += xa1 * (f32x2){bflo(U1.y), bfhi(U1.y)};
        A6 += xa1 * (f32x2){bflo(U1.z), bfhi(U1.z)};
        A7 += xa1 * (f32x2){bflo(U1.w), bfhi(U1.w)};
    }
    // ---- reduce-scatter over bits 2..5: lane ends with one channel ----
    f32x2 r0, r1, r2, r3;
    float zf;
    {   // off=4 (bit2 = head within pair, +8 ch); z scattered here too
        const bool hi = lane & 4;
        f32x2 s0 = hi ? A0 : A4, s1v = hi ? A1 : A5;
        f32x2 s2v = hi ? A2 : A6, s3v = hi ? A3 : A7;
        const f32x2 k0 = hi ? A4 : A0, k1 = hi ? A5 : A1;
        const f32x2 k2 = hi ? A6 : A2, k3 = hi ? A7 : A3;
        s0.x = __shfl_xor(s0.x, 4); s0.y = __shfl_xor(s0.y, 4);
        s1v.x = __shfl_xor(s1v.x, 4); s1v.y = __shfl_xor(s1v.y, 4);
        s2v.x = __shfl_xor(s2v.x, 4); s2v.y = __shfl_xor(s2v.y, 4);
        s3v.x = __shfl_xor(s3v.x, 4); s3v.y = __shfl_xor(s3v.y, 4);
        r0 = k0 + s0; r1 = k1 + s1v; r2 = k2 + s2v; r3 = k3 + s3v;
        float zs = hi ? z2.x : z2.y;
        const float zk = hi ? z2.y : z2.x;
        zs = __shfl_xor(zs, 4);
        zf = zk + zs;
    }
    {   // off=8 (bit3, +4 ch)
        const bool hi = lane & 8;
        f32x2 s0 = hi ? r0 : r2, s1v = hi ? r1 : r3;
        const f32x2 k0 = hi ? r2 : r0, k1 = hi ? r3 : r1;
        s0.x = __shfl_xor(s0.x, 8); s0.y = __shfl_xor(s0.y, 8);
        s1v.x = __shfl_xor(s1v.x, 8); s1v.y = __shfl_xor(s1v.y, 8);
        r0 = k0 + s0; r1 = k1 + s1v;
    }
    {   // off=16 (bit4, +2 ch)
        const bool hi = lane & 16;
        f32x2 s0 = hi ? r0 : r1;
        const f32x2 k0 = hi ? r1 : r0;
        s0.x = __shfl_xor(s0.x, 16); s0.y = __shfl_xor(s0.y, 16);
        r0 = k0 + s0;
    }
    float sv;
    {   // off=32 (bit5, +1 ch)
        const bool hi = lane & 32;
        float s0 = hi ? r0.x : r0.y;
        const float k0 = hi ? r0.y : r0.x;
        s0 = __shfl_xor(s0, 32);
        sv = k0 + s0;
    }
    zf += __shfl_xor(zf, 8); zf += __shfl_xor(zf, 16); zf += __shfl_xor(zf, 32);

    const int xi = cp * 16 + ((lane >> 2) & 1) * 8 + ((lane >> 3) & 1) * 4
                 + ((lane >> 4) & 1) * 2 + ((lane >> 5) & 1);
    const float zi = 1.f / (zf + 1e-16f);
    float xv = sv * zi + b1[xi];
    xv = xv > 0.f ? xv : __expf(xv) - 1.f;     // elu, all 64 lanes (1 each)
    sx[w][xi] = xv;                            // permutation: conflict-free
    __builtin_amdgcn_wave_barrier();           // in-wave LDS RAW ordering

    // fused node GEMM: h2[oc] = sum_k x2[k] * W2[k][oc]  (lane: kh half, oc)
    const int kh = lane >> 5;          // K half 0..1
    const int oc = lane & 31;          // output channel
    const float4* sxv = (const float4*)&sx[w][kh * 32];   // broadcast reads
    const float* wp0 = W2 + (size_t)(kh * 32) * F2 + oc;  // coalesced 128B/half
    float acc = 0.f;
#pragma unroll
    for (int k4 = 0; k4 < 8; ++k4) {
        const float4 xv4 = sxv[k4];
        const float* wp = wp0 + (size_t)k4 * 4 * F2;
        acc += xv4.x * wp[0]      + xv4.y * wp[F2]
             + xv4.z * wp[2 * F2] + xv4.w * wp[3 * F2];
    }
    acc += __shfl_xor(acc, 32);        // combine K halves; all lanes have h2[oc]

    float sA2 = acc * as2[oc], dA2 = acc * ad2[oc];
#pragma unroll
    for (int off = 1; off <= 16; off <<= 1) {
        sA2 += __shfl_xor(sA2, off);
        dA2 += __shfl_xor(dA2, off);
    }
    const float accp = __shfl_xor(acc, 1);     // partner channel (oc^1)
    if (lane < 32 && !(lane & 1))
        *(uint*)&h2b[(size_t)wid * F2 + oc] = pk2bf(acc, accp);
    if (lane == 0) { s2[wid] = sA2; d2[wid] = dA2; }
}

// ---------------------------------------------------------------------------
// K_agg2: 2 lanes/edge (32 groups; lane bit0 = channel half, 2x uint4 per
// lane). Reduce-scatter over bits 1-4 (+ combine over bit 5) leaves each
// lane one class logit; 1 exp/lane softmax tail. Writes d_out.
// ---------------------------------------------------------------------------
__global__ __launch_bounds__(256) void k_agg2(
        const int* __restrict__ row_ptr, const int* __restrict__ srcs,
        const ushort* __restrict__ h2b, const float* __restrict__ s2,
        const float* __restrict__ d2, const float* __restrict__ b2,
        float* __restrict__ out) {
    const int wid = (blockIdx.x * 256 + threadIdx.x) >> 6;
    if (wid >= N_NODES) return;
    const int lane = threadIdx.x & 63;
    const int q = lane >> 1;          // edge group 0..31
    const int ch = lane & 1;          // channel half: channels 16ch..16ch+15
    const float dn = d2[wid];
    const int beg = row_ptr[wid], end = row_ptr[wid + 1];
    const char* hP = (const char*)h2b;        // 64B rows, 6.4 MB
    const char* sP = (const char*)s2;         // 4B, 0.4 MB
    const uint ch32 = 32u * (uint)ch;
    f32x2 A0 = {0.f, 0.f}, A1 = {0.f, 0.f}, A2 = {0.f, 0.f}, A3 = {0.f, 0.f};
    f32x2 A4 = {0.f, 0.f}, A5 = {0.f, 0.f}, A6 = {0.f, 0.f}, A7 = {0.f, 0.f};
    float z = 0.f;
    for (int i = beg + q; i < end; i += 32) {
        const int nA = srcs[i];
        float eA = *(const float*)(sP + (uint)nA * 4u) + dn;
        eA = fmaxf(eA, SLOPE * eA);
        const float xA = __expf(eA);
        const uint off = (uint)nA * 64u + ch32;
        const uint4 U0 = *(const uint4*)(hP + off);
        const uint4 U1 = *(const uint4*)(hP + off + 16);
        z += xA;
        const f32x2 xa = {xA, xA};
        A0 += xa * (f32x2){bflo(U0.x), bfhi(U0.x)};
        A1 += xa * (f32x2){bflo(U0.y), bfhi(U0.y)};
        A2 += xa * (f32x2){bflo(U0.z), bfhi(U0.z)};
        A3 += xa * (f32x2){bflo(U0.w), bfhi(U0.w)};
        A4 += xa * (f32x2){bflo(U1.x), bfhi(U1.x)};
        A5 += xa * (f32x2){bflo(U1.y), bfhi(U1.y)};
        A6 += xa * (f32x2){bflo(U1.z), bfhi(U1.z)};
        A7 += xa * (f32x2){bflo(U1.w), bfhi(U1.w)};
    }
    // ---- reduce-scatter over bits 1,2,3,4; plain combine over bit 5 ----
    f32x2 r0, r1, r2, r3;
    {   // off=2 (bit1 -> rel-ch +8): 8 -> 4
        const bool hi = lane & 2;
        f32x2 s0 = hi ? A0 : A4, s1v = hi ? A1 : A5;
        f32x2 s2v = hi ? A2 : A6, s3v = hi ? A3 : A7;
        const f32x2 k0 = hi ? A4 : A0, k1 = hi ? A5 : A1;
        const f32x2 k2 = hi ? A6 : A2, k3 = hi ? A7 : A3;
        s0.x = __shfl_xor(s0.x, 2); s0.y = __shfl_xor(s0.y, 2);
        s1v.x = __shfl_xor(s1v.x, 2); s1v.y = __shfl_xor(s1v.y, 2);
        s2v.x = __shfl_xor(s2v.x, 2); s2v.y = __shfl_xor(s2v.y, 2);
        s3v.x = __shfl_xor(s3v.x, 2); s3v.y = __shfl_xor(s3v.y, 2);
        r0 = k0 + s0; r1 = k1 + s1v; r2 = k2 + s2v; r3 = k3 + s3v;
    }
    {   // off=4 (bit2 -> rel-ch +4): 4 -> 2
        const bool hi = lane & 4;
        f32x2 s0 = hi ? r0 : r2, s1v = hi ? r1 : r3;
        const f32x2 k0 = hi ? r2 : r0, k1 = hi ? r3 : r1;
        s0.x = __shfl_xor(s0.x, 4); s0.y = __shfl_xor(s0.y, 4);
        s1v.x = __shfl_xor(s1v.x, 4); s1v.y = __shfl_xor(s1v.y, 4);
        r0 = k0 + s0; r1 = k1 + s1v;
    }
    {   // off=8 (bit3 -> rel-ch +2): 2 -> 1
        const bool hi = lane & 8;
        f32x2 s0 = hi ? r0 : r1;
        const f32x2 k0 = hi ? r1 : r0;
        s0.x = __shfl_xor(s0.x, 8); s0.y = __shfl_xor(s0.y, 8);
        r0 = k0 + s0;
    }
    float sv;
    {   // off=16 (bit4 -> rel-ch +1): f32x2 -> float
        const bool hi = lane & 16;
        float s0 = hi ? r0.x : r0.y;
        const float k0 = hi ? r0.y : r0.x;
        s0 = __shfl_xor(s0, 16);
        sv = k0 + s0;
    }
    sv += __shfl_xor(sv, 32);          // lanes l, l^32 now duplicate
    z += __shfl_xor(z, 2); z += __shfl_xor(z, 4); z += __shfl_xor(z, 8);
    z += __shfl_xor(z, 16); z += __shfl_xor(z, 32);

    const int elem = ch * 16 + ((lane >> 1) & 1) * 8 + ((lane >> 2) & 1) * 4
                   + ((lane >> 3) & 1) * 2 + ((lane >> 4) & 1);
    const float zi = 1.f / (z + 1e-16f);
    const float v = sv * zi + b2[elem];
    // log-softmax over the 32 classes: each 32-lane half holds all 32 once.
    float m = v;
#pragma unroll
    for (int off = 1; off <= 16; off <<= 1) m = fmaxf(m, __shfl_xor(m, off));
    float ssum = __expf(v - m);
#pragma unroll
    for (int off = 1; off <= 16; off <<= 1) ssum += __shfl_xor(ssum, off);
    const float lse = m + __logf(ssum);
    if (lane < 32) out[(size_t)wid * F2 + elem] = v - lse;
}

extern "C" void kernel_launch(void* const* d_in, const int* in_sizes, int n_in,
                              void* d_out, int out_size, void* d_ws, size_t ws_size,
                              hipStream_t stream) {
    const float* x   = (const float*)d_in[0];
    const int*   ei  = (const int*)d_in[1];
    const float* W1  = (const float*)d_in[2];
    const float* as1 = (const float*)d_in[3];
    const float* ad1 = (const float*)d_in[4];
    const float* b1  = (const float*)d_in[5];
    const float* W2  = (const float*)d_in[6];
    const float* as2 = (const float*)d_in[7];
    const float* ad2 = (const float*)d_in[8];
    const float* b2  = (const float*)d_in[9];
    float* out = (float*)d_out;

    // Workspace layout (xb removed: x read f32 directly by the gemm)
    ushort* h1b = (ushort*)d_ws;                   // N*64 bf16 (128B rows)
    ushort* h2b = h1b + (size_t)N_NODES * F1;      // N*32 bf16
    ushort* w1b = h2b + (size_t)N_NODES * F2;      // 16384 bf16 (swizzled W1)
    float*  s1  = (float*)(w1b + F_IN * F1);       // N*8
    float*  d1  = s1 + (size_t)N_NODES * H1;       // N*8
    float*  s2  = d1 + (size_t)N_NODES * H1;       // N
    float*  d2  = s2 + N_NODES;                    // N
    uint*   tmp = (uint*)(d2 + N_NODES);           // N_EDGES (packed)
    int* row_ptr = (int*)(tmp + N_EDGES);          // N+1
    int* colsum  = row_ptr + N_NODES + 1;          // NBKT
    int* bcnt    = colsum + NBKT;                  // NBKT*NB1
    int* srcs    = bcnt + (size_t)NBKT * NB1;      // N_TOT

    const int nb_w = (N_NODES * 64 + 255) / 256;   // one wave per node

    k_p1w<<<NB1 + 1, 256, 0, stream>>>(ei, W1, bcnt, w1b);
    k_p2<<<NBKT, 64, 0, stream>>>(bcnt, colsum);
    k_p3<<<NB1, 256, 0, stream>>>(ei, bcnt, colsum, tmp);
    k_final_gemm<<<NBKT + NB_G2, 256, 0, stream>>>(tmp, colsum, row_ptr, srcs,
                                                   x, w1b, as1, ad1,
                                                   h1b, s1, d1);
    k_agg1<<<nb_w, 256, 0, stream>>>(row_ptr, srcs, h1b, s1, d1, b1,
                                     W2, as2, ad2, h2b, s2, d2);
    k_agg2<<<nb_w, 256, 0, stream>>>(row_ptr, srcs, h2b, s2, d2, b2, out);
}

// Round 11
// 325.974 us; speedup vs baseline: 1.0870x; 1.0241x over previous
//
#include <hip/hip_runtime.h>
#include <hip/hip_bf16.h>

#define N_NODES 100000
#define N_EDGES 1600000
#define N_TOT   (N_EDGES + N_NODES)   // edges + self loops
#define F_IN    256
#define F1      64     // H1*C1
#define H1      8
#define C1      8
#define F2      32
#define SLOPE   0.2f

#define NB_G2   ((N_NODES + 63) / 64)             // 1563 gemm blocks (64 rows each)

// counting-sort CSR build (single kernel, block-aggregated reservation)
#define EB      4096                               // edges per sort block
#define NB1     ((N_EDGES + EB - 1) / EB)          // 391
#define BW      256                                // nodes per bucket
#define NBKT    ((N_NODES + BW - 1) / BW)          // 391
#define MAXB    5120                               // padded bucket region (mean 4096, sigma 64)

typedef unsigned int  uint;
typedef unsigned short ushort;
typedef __attribute__((ext_vector_type(8))) short bf16x8;
typedef __attribute__((ext_vector_type(4))) float f32x4;
typedef __attribute__((ext_vector_type(2))) float f32x2;

__device__ inline ushort f2bf(float f) {               // RNE float->bf16
    uint u = __float_as_uint(f);
    uint r = u + 0x7fffu + ((u >> 16) & 1u);
    return (ushort)(r >> 16);
}
__device__ inline float bflo(uint u) { return __uint_as_float(u << 16); }
__device__ inline float bfhi(uint u) { return __uint_as_float(u & 0xffff0000u); }
__device__ inline uint pk2bf(float a, float b) {
    __hip_bfloat162 h = __float22bfloat162_rn(make_float2(a, b));
    union { __hip_bfloat162 h; uint u; } cv; cv.h = h;
    return cv.u;
}

// Block-wide exclusive scan of cnt[NBKT] -> sb[0..NBKT] (sb[NBKT]=total).
__device__ inline void bucket_bases(const int* __restrict__ cnts,
                                    int* sc, int* sb, int tid) {
    const int i0 = 2 * tid, i1 = 2 * tid + 1;
    const int a0 = (i0 < NBKT) ? cnts[i0] : 0;
    const int a1 = (i1 < NBKT) ? cnts[i1] : 0;
    sc[tid] = a0 + a1;
    __syncthreads();
    for (int off = 1; off < 256; off <<= 1) {
        int t = (tid >= off) ? sc[tid - off] : 0;
        __syncthreads();
        sc[tid] += t;
        __syncthreads();
    }
    const int excl = sc[tid] - (a0 + a1);
    if (i0 < NBKT)  sb[i0] = excl;
    if (i1 <= NBKT) sb[i1] = excl + a0;       // writes sb[NBKT] (=total) too
    __syncthreads();
}

// ---------------------------------------------------------------------------
// K_sort: SINGLE-LAUNCH bucket sort (replaces old p1w-hist + p2 + p3).
// Per 4096-edge block: LDS histogram -> ONE global atomicAdd per bucket
// (391x391 = 153K well-spread atomics, ~2-3us; NOT the 1.6M edge-atomic
// wall) reserving a range in the padded per-bucket region tmp[b*MAXB..],
// then scatter via LDS cursors. Within-bucket order is nondeterministic;
// k_final re-ranks per node so srcs per-node sets are unchanged.
// Block NB1 = W1 swizzled bf16 pre-convert.
// ---------------------------------------------------------------------------
__global__ __launch_bounds__(256) void k_sort(
        const int* __restrict__ ei, const float* __restrict__ W1,
        int* __restrict__ gcnt, uint* __restrict__ tmp,
        ushort* __restrict__ w1b) {
    __shared__ int HC[NBKT];
    const int tid = threadIdx.x;
    if (blockIdx.x == NB1) {                       // ---- W1 convert ----
        for (int i = 0; i < 64; ++i) {
            const int e = i * 256 + tid;           // e = k*64 + n
            const int k = e >> 6, n = e & 63;
            w1b[((k >> 3) * 64 + n) * 8 + (k & 7)] = f2bf(W1[e]);
        }
        return;
    }
    const int blk = blockIdx.x;
    for (int j = tid; j < NBKT; j += 256) HC[j] = 0;
    __syncthreads();
    const int e0 = blk * EB;
    const int lim = (e0 + EB < N_EDGES) ? e0 + EB : N_EDGES;
    for (int i = e0 + tid * 2; i < lim; i += 512) {    // (lim-e0) % 512 == 0
        const int2 dd = *(const int2*)&ei[N_EDGES + i];
        atomicAdd(&HC[dd.x >> 8], 1);              // LDS atomic
        atomicAdd(&HC[dd.y >> 8], 1);
    }
    __syncthreads();
    for (int b = tid; b < NBKT; b += 256) {        // reserve ranges
        const int c = HC[b];
        const int base = c ? atomicAdd(&gcnt[b], c) : 0;   // global, 1/bucket
        HC[b] = b * MAXB + base;                   // becomes scatter cursor
    }
    __syncthreads();
    for (int i = e0 + tid * 2; i < lim; i += 512) {
        const int2 ss = *(const int2*)&ei[i];
        const int2 dd = *(const int2*)&ei[N_EDGES + i];
        const int p0 = atomicAdd(&HC[dd.x >> 8], 1);       // LDS atomic
        tmp[p0] = ((uint)(dd.x & 255) << 24) | (uint)ss.x;
        const int p1 = atomicAdd(&HC[dd.y >> 8], 1);
        tmp[p1] = ((uint)(dd.y & 255) << 24) | (uint)ss.y;
    }
}

// ---------------------------------------------------------------------------
// Launch 3: blocks [0,NBKT) = final CSR placement (bucket bases from a
// block-local prefix scan of gcnt); blocks [NBKT,NBKT+NB_G2) = MFMA gemm,
// 64 rows/block (4 waves x 16 rows), B-frags direct from global w1b
// (L2-broadcast), A read f32 + inline pk2bf.
// ---------------------------------------------------------------------------
__global__ __launch_bounds__(256) void k_final_gemm(
        const uint* __restrict__ tmp, const int* __restrict__ gcnt,
        int* __restrict__ row_ptr, int* __restrict__ srcs,
        const float* __restrict__ x, const ushort* __restrict__ w1b,
        const float* __restrict__ as1, const float* __restrict__ ad1,
        ushort* __restrict__ h1b, float* __restrict__ s1,
        float* __restrict__ d1) {
    __shared__ union {
        struct { int sc[256]; int sb[NBKT + 1]; int cur[BW]; } f;
        ushort S[4][16][66];        // 8.4 KB per-wave h staging (pad 66)
    } sm;
    const int tid = threadIdx.x;

    if (blockIdx.x < NBKT) {                       // ---- final placement ----
        const int b = blockIdx.x;
        bucket_bases(gcnt, sm.f.sc, sm.f.sb, tid); // sb = edge-count prefix
        sm.f.cur[tid] = 0;
        __syncthreads();
        const int lo = b * MAXB;                   // padded tmp region
        const int hi = lo + (sm.f.sb[b + 1] - sm.f.sb[b]);
        for (int i = lo + tid; i < hi; i += 256)
            atomicAdd(&sm.f.cur[tmp[i] >> 24], 1);      // LDS atomic
        __syncthreads();
        const int n = b * BW + tid;
        const int myc = sm.f.cur[tid];
        const int v = (n < N_NODES) ? myc + 1 : 0;      // +1 = self loop
        __syncthreads();
        sm.f.sc[tid] = v;
        __syncthreads();
        for (int off = 1; off < 256; off <<= 1) {
            int t = (tid >= off) ? sm.f.sc[tid - off] : 0;
            __syncthreads();
            sm.f.sc[tid] += t;
            __syncthreads();
        }
        const int rp = sm.f.sb[b] + b * BW + (sm.f.sc[tid] - v);
        if (n < N_NODES) {
            row_ptr[n] = rp;
            srcs[rp] = n;                               // self loop slot 0
        }
        if (b == NBKT - 1 && tid == 255) row_ptr[N_NODES] = N_TOT;
        sm.f.cur[tid] = rp + 1;                         // edge cursor
        __syncthreads();
        for (int i = lo + tid; i < hi; i += 256) {
            const uint u = tmp[i];
            const int pos = atomicAdd(&sm.f.cur[u >> 24], 1);   // LDS atomic
            srcs[pos] = (int)(u & 0xFFFFFFu);
        }
        return;
    }

    // ---- MFMA gemm part: 64 rows, 4 waves x 16 rows ----
    const int wave = tid >> 6, lane = tid & 63;
    const int q = lane >> 4, ln = lane & 15;
    const int rowbase = (blockIdx.x - NBKT) * 64 + wave * 16;
    const int row = rowbase + ln;
    const int rowc = row < N_NODES ? row : N_NODES - 1;
    const float* xr = x + (size_t)rowc * F_IN + q * 8;

    f32x4 acc[4];
#pragma unroll
    for (int nt = 0; nt < 4; ++nt) acc[nt] = (f32x4){0.f, 0.f, 0.f, 0.f};

#pragma unroll 4
    for (int t = 0; t < 8; ++t) {                  // K-loop: 8 x 32
        const float4 a0 = *(const float4*)(xr + t * 32);
        const float4 a1 = *(const float4*)(xr + t * 32 + 4);
        uint4 au = make_uint4(pk2bf(a0.x, a0.y), pk2bf(a0.z, a0.w),
                              pk2bf(a1.x, a1.y), pk2bf(a1.z, a1.w));
        bf16x8 af = *(bf16x8*)&au;
        bf16x8 bfr[4];
#pragma unroll
        for (int nt = 0; nt < 4; ++nt)
            bfr[nt] = *(const bf16x8*)&w1b[((t * 4 + q) * 64 + nt * 16 + ln) * 8];
#pragma unroll
        for (int nt = 0; nt < 4; ++nt)
            acc[nt] = __builtin_amdgcn_mfma_f32_16x16x32_bf16(
                          af, bfr[nt], acc[nt], 0, 0, 0);
    }

    // stage h (bf16): C/D layout col=lane&15 (channel), row=q*4+r (node)
#pragma unroll
    for (int nt = 0; nt < 4; ++nt)
#pragma unroll
        for (int r = 0; r < 4; ++r)
            sm.S[wave][q * 4 + r][nt * 16 + ln] = f2bf(acc[nt][r]);
    __builtin_amdgcn_wave_barrier();               // per-wave staging

    if (lane >= 16) return;
    const int node = rowbase + lane;
    if (node >= N_NODES) return;
    const uint* srow = (const uint*)&sm.S[wave][lane][0];
    float sacc[H1], dacc[H1];
#pragma unroll
    for (int h = 0; h < H1; ++h) { sacc[h] = 0.f; dacc[h] = 0.f; }
    uint4* hout = (uint4*)(h1b + (size_t)node * F1);
#pragma unroll
    for (int p4 = 0; p4 < 8; ++p4) {               // p4 == head index
        const uint u0 = srow[p4 * 4 + 0], u1 = srow[p4 * 4 + 1];
        const uint u2 = srow[p4 * 4 + 2], u3 = srow[p4 * 4 + 3];
        hout[p4] = make_uint4(u0, u1, u2, u3);
        const float c[8] = {bflo(u0), bfhi(u0), bflo(u1), bfhi(u1),
                            bflo(u2), bfhi(u2), bflo(u3), bfhi(u3)};
#pragma unroll
        for (int j = 0; j < 8; ++j) {
            sacc[p4] += c[j] * as1[p4 * 8 + j];
            dacc[p4] += c[j] * ad1[p4 * 8 + j];
        }
    }
    float4* s4 = (float4*)(s1 + (size_t)node * H1);
    float4* d4 = (float4*)(d1 + (size_t)node * H1);
    s4[0] = make_float4(sacc[0], sacc[1], sacc[2], sacc[3]);
    s4[1] = make_float4(sacc[4], sacc[5], sacc[6], sacc[7]);
    d4[0] = make_float4(dacc[0], dacc[1], dacc[2], dacc[3]);
    d4[1] = make_float4(dacc[4], dacc[5], dacc[6], dacc[7]);
}

// ---------------------------------------------------------------------------
// K_agg1 (+ fused node GEMM): 4 lanes/edge (16 groups); lane owns a head
// PAIR. Structural floor confirmed (R8/R9): bound by random 128B gathers
// (69% forced L2 miss: 12.8MB table vs 4MB/XCD L2) + ~74% VALU issue.
// ---------------------------------------------------------------------------
__global__ __launch_bounds__(256) void k_agg1(
        const int* __restrict__ row_ptr, const int* __restrict__ srcs,
        const ushort* __restrict__ h1b, const float* __restrict__ s1,
        const float* __restrict__ d1, const float* __restrict__ b1,
        const float* __restrict__ W2, const float* __restrict__ as2,
        const float* __restrict__ ad2,
        ushort* __restrict__ h2b, float* __restrict__ s2,
        float* __restrict__ d2) {
    __shared__ float sx[4][64];                    // per-wave x2 row (f32)
    const int wid = (blockIdx.x * 256 + threadIdx.x) >> 6;
    if (wid >= N_NODES) return;
    const int w = threadIdx.x >> 6;
    const int lane = threadIdx.x & 63;
    const int q = lane >> 2;          // edge group 0..15
    const int cp = lane & 3;          // head pair: heads 2cp, 2cp+1
    const float2 dh2 = *(const float2*)((const char*)d1 + (size_t)wid * 32 + 8 * cp);
    const int beg = row_ptr[wid], end = row_ptr[wid + 1];
    const char* hP = (const char*)h1b;        // 128B rows, 12.8 MB
    const char* sP = (const char*)s1;         // 32B rows, 3.2 MB
    const uint hOff = 32u * (uint)cp;
    const uint sOff = 8u * (uint)cp;
    f32x2 A0 = {0.f, 0.f}, A1 = {0.f, 0.f}, A2 = {0.f, 0.f}, A3 = {0.f, 0.f};
    f32x2 A4 = {0.f, 0.f}, A5 = {0.f, 0.f}, A6 = {0.f, 0.f}, A7 = {0.f, 0.f};
    f32x2 z2 = {0.f, 0.f};
    for (int i = beg + q; i < end; i += 16) {
        const int nA = srcs[i];
        const float2 sv2 = *(const float2*)(sP + ((uint)nA * 32u + sOff));
        float e0 = sv2.x + dh2.x, e1 = sv2.y + dh2.y;
        e0 = fmaxf(e0, SLOPE * e0);            // leaky (slope<1)
        e1 = fmaxf(e1, SLOPE * e1);
        const float x0 = __expf(e0), x1 = __expf(e1);
        const uint base = (uint)nA * 128u + hOff;
        const uint4 U0 = *(const uint4*)(hP + base);
        const uint4 U1 = *(const uint4*)(hP + base + 16);
        z2 += (f32x2){x0, x1};
        const f32x2 xa0 = {x0, x0}, xa1 = {x1, x1};
        A0 += xa0 * (f32x2){bflo(U0.x), bfhi(U0.x)};
        A1 += xa0 * (f32x2){bflo(U0.y), bfhi(U0.y)};
        A2 += xa0 * (f32x2){bflo(U0.z), bfhi(U0.z)};
        A3 += xa0 * (f32x2){bflo(U0.w), bfhi(U0.w)};
        A4 += xa1 * (f32x2){bflo(U1.x), bfhi(U1.x)};
        A5 += xa1 * (f32x2){bflo(U1.y), bfhi(U1.y)};
        A6 += xa1 * (f32x2){bflo(U1.z), bfhi(U1.z)};
        A7 += xa1 * (f32x2){bflo(U1.w), bfhi(U1.w)};
    }
    // ---- reduce-scatter over bits 2..5: lane ends with one channel ----
    f32x2 r0, r1, r2, r3;
    float zf;
    {   // off=4 (bit2 = head within pair, +8 ch); z scattered here too
        const bool hi = lane & 4;
        f32x2 s0 = hi ? A0 : A4, s1v = hi ? A1 : A5;
        f32x2 s2v = hi ? A2 : A6, s3v = hi ? A3 : A7;
        const f32x2 k0 = hi ? A4 : A0, k1 = hi ? A5 : A1;
        const f32x2 k2 = hi ? A6 : A2, k3 = hi ? A7 : A3;
        s0.x = __shfl_xor(s0.x, 4); s0.y = __shfl_xor(s0.y, 4);
        s1v.x = __shfl_xor(s1v.x, 4); s1v.y = __shfl_xor(s1v.y, 4);
        s2v.x = __shfl_xor(s2v.x, 4); s2v.y = __shfl_xor(s2v.y, 4);
        s3v.x = __shfl_xor(s3v.x, 4); s3v.y = __shfl_xor(s3v.y, 4);
        r0 = k0 + s0; r1 = k1 + s1v; r2 = k2 + s2v; r3 = k3 + s3v;
        float zs = hi ? z2.x : z2.y;
        const float zk = hi ? z2.y : z2.x;
        zs = __shfl_xor(zs, 4);
        zf = zk + zs;
    }
    {   // off=8 (bit3, +4 ch)
        const bool hi = lane & 8;
        f32x2 s0 = hi ? r0 : r2, s1v = hi ? r1 : r3;
        const f32x2 k0 = hi ? r2 : r0, k1 = hi ? r3 : r1;
        s0.x = __shfl_xor(s0.x, 8); s0.y = __shfl_xor(s0.y, 8);
        s1v.x = __shfl_xor(s1v.x, 8); s1v.y = __shfl_xor(s1v.y, 8);
        r0 = k0 + s0; r1 = k1 + s1v;
    }
    {   // off=16 (bit4, +2 ch)
        const bool hi = lane & 16;
        f32x2 s0 = hi ? r0 : r1;
        const f32x2 k0 = hi ? r1 : r0;
        s0.x = __shfl_xor(s0.x, 16); s0.y = __shfl_xor(s0.y, 16);
        r0 = k0 + s0;
    }
    float sv;
    {   // off=32 (bit5, +1 ch)
        const bool hi = lane & 32;
        float s0 = hi ? r0.x : r0.y;
        const float k0 = hi ? r0.y : r0.x;
        s0 = __shfl_xor(s0, 32);
        sv = k0 + s0;
    }
    zf += __shfl_xor(zf, 8); zf += __shfl_xor(zf, 16); zf += __shfl_xor(zf, 32);

    const int xi = cp * 16 + ((lane >> 2) & 1) * 8 + ((lane >> 3) & 1) * 4
                 + ((lane >> 4) & 1) * 2 + ((lane >> 5) & 1);
    const float zi = 1.f / (zf + 1e-16f);
    float xv = sv * zi + b1[xi];
    xv = xv > 0.f ? xv : __expf(xv) - 1.f;     // elu, all 64 lanes (1 each)
    sx[w][xi] = xv;                            // permutation: conflict-free
    __builtin_amdgcn_wave_barrier();           // in-wave LDS RAW ordering

    // fused node GEMM: h2[oc] = sum_k x2[k] * W2[k][oc]  (lane: kh half, oc)
    const int kh = lane >> 5;          // K half 0..1
    const int oc = lane & 31;          // output channel
    const float4* sxv = (const float4*)&sx[w][kh * 32];   // broadcast reads
    const float* wp0 = W2 + (size_t)(kh * 32) * F2 + oc;  // coalesced 128B/half
    float acc = 0.f;
#pragma unroll
    for (int k4 = 0; k4 < 8; ++k4) {
        const float4 xv4 = sxv[k4];
        const float* wp = wp0 + (size_t)k4 * 4 * F2;
        acc += xv4.x * wp[0]      + xv4.y * wp[F2]
             + xv4.z * wp[2 * F2] + xv4.w * wp[3 * F2];
    }
    acc += __shfl_xor(acc, 32);        // combine K halves; all lanes have h2[oc]

    float sA2 = acc * as2[oc], dA2 = acc * ad2[oc];
#pragma unroll
    for (int off = 1; off <= 16; off <<= 1) {
        sA2 += __shfl_xor(sA2, off);
        dA2 += __shfl_xor(dA2, off);
    }
    const float accp = __shfl_xor(acc, 1);     // partner channel (oc^1)
    if (lane < 32 && !(lane & 1))
        *(uint*)&h2b[(size_t)wid * F2 + oc] = pk2bf(acc, accp);
    if (lane == 0) { s2[wid] = sA2; d2[wid] = dA2; }
}

// ---------------------------------------------------------------------------
// K_agg2: 2 lanes/edge (32 groups; lane bit0 = channel half, 2x uint4 per
// lane). Reduce-scatter over bits 1-4 (+ combine over bit 5) leaves each
// lane one class logit; 1 exp/lane softmax tail. Writes d_out.
// ---------------------------------------------------------------------------
__global__ __launch_bounds__(256) void k_agg2(
        const int* __restrict__ row_ptr, const int* __restrict__ srcs,
        const ushort* __restrict__ h2b, const float* __restrict__ s2,
        const float* __restrict__ d2, const float* __restrict__ b2,
        float* __restrict__ out) {
    const int wid = (blockIdx.x * 256 + threadIdx.x) >> 6;
    if (wid >= N_NODES) return;
    const int lane = threadIdx.x & 63;
    const int q = lane >> 1;          // edge group 0..31
    const int ch = lane & 1;          // channel half: channels 16ch..16ch+15
    const float dn = d2[wid];
    const int beg = row_ptr[wid], end = row_ptr[wid + 1];
    const char* hP = (const char*)h2b;        // 64B rows, 6.4 MB
    const char* sP = (const char*)s2;         // 4B, 0.4 MB
    const uint ch32 = 32u * (uint)ch;
    f32x2 A0 = {0.f, 0.f}, A1 = {0.f, 0.f}, A2 = {0.f, 0.f}, A3 = {0.f, 0.f};
    f32x2 A4 = {0.f, 0.f}, A5 = {0.f, 0.f}, A6 = {0.f, 0.f}, A7 = {0.f, 0.f};
    float z = 0.f;
    for (int i = beg + q; i < end; i += 32) {
        const int nA = srcs[i];
        float eA = *(const float*)(sP + (uint)nA * 4u) + dn;
        eA = fmaxf(eA, SLOPE * eA);
        const float xA = __expf(eA);
        const uint off = (uint)nA * 64u + ch32;
        const uint4 U0 = *(const uint4*)(hP + off);
        const uint4 U1 = *(const uint4*)(hP + off + 16);
        z += xA;
        const f32x2 xa = {xA, xA};
        A0 += xa * (f32x2){bflo(U0.x), bfhi(U0.x)};
        A1 += xa * (f32x2){bflo(U0.y), bfhi(U0.y)};
        A2 += xa * (f32x2){bflo(U0.z), bfhi(U0.z)};
        A3 += xa * (f32x2){bflo(U0.w), bfhi(U0.w)};
        A4 += xa * (f32x2){bflo(U1.x), bfhi(U1.x)};
        A5 += xa * (f32x2){bflo(U1.y), bfhi(U1.y)};
        A6 += xa * (f32x2){bflo(U1.z), bfhi(U1.z)};
        A7 += xa * (f32x2){bflo(U1.w), bfhi(U1.w)};
    }
    // ---- reduce-scatter over bits 1,2,3,4; plain combine over bit 5 ----
    f32x2 r0, r1, r2, r3;
    {   // off=2 (bit1 -> rel-ch +8): 8 -> 4
        const bool hi = lane & 2;
        f32x2 s0 = hi ? A0 : A4, s1v = hi ? A1 : A5;
        f32x2 s2v = hi ? A2 : A6, s3v = hi ? A3 : A7;
        const f32x2 k0 = hi ? A4 : A0, k1 = hi ? A5 : A1;
        const f32x2 k2 = hi ? A6 : A2, k3 = hi ? A7 : A3;
        s0.x = __shfl_xor(s0.x, 2); s0.y = __shfl_xor(s0.y, 2);
        s1v.x = __shfl_xor(s1v.x, 2); s1v.y = __shfl_xor(s1v.y, 2);
        s2v.x = __shfl_xor(s2v.x, 2); s2v.y = __shfl_xor(s2v.y, 2);
        s3v.x = __shfl_xor(s3v.x, 2); s3v.y = __shfl_xor(s3v.y, 2);
        r0 = k0 + s0; r1 = k1 + s1v; r2 = k2 + s2v; r3 = k3 + s3v;
    }
    {   // off=4 (bit2 -> rel-ch +4): 4 -> 2
        const bool hi = lane & 4;
        f32x2 s0 = hi ? r0 : r2, s1v = hi ? r1 : r3;
        const f32x2 k0 = hi ? r2 : r0, k1 = hi ? r3 : r1;
        s0.x = __shfl_xor(s0.x, 4); s0.y = __shfl_xor(s0.y, 4);
        s1v.x = __shfl_xor(s1v.x, 4); s1v.y = __shfl_xor(s1v.y, 4);
        r0 = k0 + s0; r1 = k1 + s1v;
    }
    {   // off=8 (bit3 -> rel-ch +2): 2 -> 1
        const bool hi = lane & 8;
        f32x2 s0 = hi ? r0 : r1;
        const f32x2 k0 = hi ? r1 : r0;
        s0.x = __shfl_xor(s0.x, 8); s0.y = __shfl_xor(s0.y, 8);
        r0 = k0 + s0;
    }
    float sv;
    {   // off=16 (bit4 -> rel-ch +1): f32x2 -> float
        const bool hi = lane & 16;
        float s0 = hi ? r0.x : r0.y;
        const float k0 = hi ? r0.y : r0.x;
        s0 = __shfl_xor(s0, 16);
        sv = k0 + s0;
    }
    sv += __shfl_xor(sv, 32);          // lanes l, l^32 now duplicate
    z += __shfl_xor(z, 2); z += __shfl_xor(z, 4); z += __shfl_xor(z, 8);
    z += __shfl_xor(z, 16); z += __shfl_xor(z, 32);

    const int elem = ch * 16 + ((lane >> 1) & 1) * 8 + ((lane >> 2) & 1) * 4
                   + ((lane >> 3) & 1) * 2 + ((lane >> 4) & 1);
    const float zi = 1.f / (z + 1e-16f);
    const float v = sv * zi + b2[elem];
    // log-softmax over the 32 classes: each 32-lane half holds all 32 once.
    float m = v;
#pragma unroll
    for (int off = 1; off <= 16; off <<= 1) m = fmaxf(m, __shfl_xor(m, off));
    float ssum = __expf(v - m);
#pragma unroll
    for (int off = 1; off <= 16; off <<= 1) ssum += __shfl_xor(ssum, off);
    const float lse = m + __logf(ssum);
    if (lane < 32) out[(size_t)wid * F2 + elem] = v - lse;
}

extern "C" void kernel_launch(void* const* d_in, const int* in_sizes, int n_in,
                              void* d_out, int out_size, void* d_ws, size_t ws_size,
                              hipStream_t stream) {
    const float* x   = (const float*)d_in[0];
    const int*   ei  = (const int*)d_in[1];
    const float* W1  = (const float*)d_in[2];
    const float* as1 = (const float*)d_in[3];
    const float* ad1 = (const float*)d_in[4];
    const float* b1  = (const float*)d_in[5];
    const float* W2  = (const float*)d_in[6];
    const float* as2 = (const float*)d_in[7];
    const float* ad2 = (const float*)d_in[8];
    const float* b2  = (const float*)d_in[9];
    float* out = (float*)d_out;

    // Workspace layout (bcnt/colsum removed; tmp padded per-bucket)
    ushort* h1b = (ushort*)d_ws;                   // N*64 bf16 (128B rows)
    ushort* h2b = h1b + (size_t)N_NODES * F1;      // N*32 bf16
    ushort* w1b = h2b + (size_t)N_NODES * F2;      // 16384 bf16 (swizzled W1)
    float*  s1  = (float*)(w1b + F_IN * F1);       // N*8
    float*  d1  = s1 + (size_t)N_NODES * H1;       // N*8
    float*  s2  = d1 + (size_t)N_NODES * H1;       // N
    float*  d2  = s2 + N_NODES;                    // N
    int*    gcnt = (int*)(d2 + N_NODES);           // NBKT
    uint*   tmp = (uint*)(gcnt + NBKT);            // NBKT*MAXB (padded, 8MB)
    int* row_ptr = (int*)(tmp + (size_t)NBKT * MAXB);  // N+1
    int* srcs    = row_ptr + N_NODES + 1;          // N_TOT

    const int nb_w = (N_NODES * 64 + 255) / 256;   // one wave per node

    hipMemsetAsync(gcnt, 0, (size_t)NBKT * sizeof(int), stream);
    k_sort<<<NB1 + 1, 256, 0, stream>>>(ei, W1, gcnt, tmp, w1b);
    k_final_gemm<<<NBKT + NB_G2, 256, 0, stream>>>(tmp, gcnt, row_ptr, srcs,
                                                   x, w1b, as1, ad1,
                                                   h1b, s1, d1);
    k_agg1<<<nb_w, 256, 0, stream>>>(row_ptr, srcs, h1b, s1, d1, b1,
                                     W2, as2, ad2, h2b, s2, d2);
    k_agg2<<<nb_w, 256, 0, stream>>>(row_ptr, srcs, h2b, s2, d2, b2, out);
}